// Round 1
// 530.360 us; speedup vs baseline: 1.0321x; 1.0321x over previous
//
#include <hip/hip_runtime.h>
#include <hip/hip_bf16.h>

#define NE 1600000
#define NN 100000
#define H 64
#define ED 16
#define NT (NE / 64)        // 25000 edge tiles
#define NB1 391             // ceil(NN/256) scan blocks
#define NNB 1563            // ceil(NN/64) node tiles

#define KS  72    // bf16 K-stride for K=64 packs (W1ab, W2, sH)
#define K3S 136   // bf16 row stride, node GEMM (K=128)
#define YS  68    // fp32 row stride for ysum / message buffer

typedef __attribute__((ext_vector_type(8))) short short8;
typedef __attribute__((ext_vector_type(4))) float floatx4;

__device__ __forceinline__ unsigned short f2bf(float f) {
    union { float f; unsigned u; } v; v.f = f;
    unsigned r = v.u + 0x7fff + ((v.u >> 16) & 1);
    return (unsigned short)(r >> 16);
}

__device__ __forceinline__ float bf2f(unsigned short u) {
    union { unsigned u; float f; } v; v.u = ((unsigned)u) << 16;
    return v.f;
}

// v_cvt_pk_bf16_f32: packs 2 f32 -> 2 bf16 (RNE) in ONE VALU op.
// lo -> D[15:0], hi -> D[31:16] (little-endian ushort order).
__device__ __forceinline__ unsigned cvt_pk_bf16(float lo, float hi) {
    unsigned r;
    asm("v_cvt_pk_bf16_f32 %0, %1, %2" : "=v"(r) : "v"(lo), "v"(hi));
    return r;
}

// silu via fast rcp (1 instr) instead of IEEE divide (~10 instr);
// ~1e-7 rel error, irrelevant at 0.03 tolerance.
__device__ __forceinline__ float silu(float x) {
    return x * __builtin_amdgcn_rcpf(1.0f + __expf(-x));
}

// ---- prep: x->bf16, weight packs, histogram (fused) --------------------
__global__ void prep_kernel(const float* __restrict__ x,
                            const float* __restrict__ W1,
                            const float* __restrict__ b1,
                            const float* __restrict__ W2,
                            const float* __restrict__ W3,
                            const int* __restrict__ ei,
                            unsigned short* __restrict__ xb,
                            unsigned short* __restrict__ W1abT,
                            unsigned short* __restrict__ W1cT,
                            unsigned short* __restrict__ W2T,
                            unsigned short* __restrict__ W3T,
                            int* __restrict__ cnt) {
    int tid = blockIdx.x * blockDim.x + threadIdx.x;
    int nt = gridDim.x * blockDim.x;
    const float4* xv = (const float4*)x;
    uint2* xbv = (uint2*)xb;
    for (int i = tid; i < NN * H / 4; i += nt) {
        float4 v = xv[i];
        uint2 o;
        o.x = cvt_pk_bf16(v.x, v.y);
        o.y = cvt_pk_bf16(v.z, v.w);
        xbv[i] = o;
    }
    // W1abT[n][k]: n<64 -> W1[k][n] (x_src part); n in 64..127 -> W1[64+k][n-64]
    for (int i = tid; i < 128 * KS; i += nt) {
        int n = i / KS, k = i % KS;
        W1abT[i] = (k < 64) ? f2bf(W1[(size_t)((n < 64) ? k : 64 + k) * 64 + (n & 63)])
                            : (unsigned short)0;
    }
    // W1cT[n][k]: k<16 -> W1[128+k][n]; k==16 -> b1[n] (bias slot); else 0
    for (int i = tid; i < 64 * 32; i += nt) {
        int n = i / 32, k = i % 32;
        unsigned short v = 0;
        if (k < 16) v = f2bf(W1[(size_t)(128 + k) * 64 + n]);
        else if (k == 16) v = f2bf(b1[n]);
        W1cT[i] = v;
    }
    for (int i = tid; i < 64 * KS; i += nt) {
        int n = i / KS, k = i % KS;
        W2T[i] = (k < 64) ? f2bf(W2[k * 64 + n]) : (unsigned short)0;
    }
    for (int i = tid; i < 64 * K3S; i += nt) {
        int n = i / K3S, k = i % K3S;
        W3T[i] = (k < 128) ? f2bf(W3[k * 64 + n]) : (unsigned short)0;
    }
    // histogram of dst
    for (int e = tid; e < NE; e += nt) {
        atomicAdd(&cnt[ei[NE + e]], 1);
    }
}

// ---- counting-sort scan ------------------------------------------------
__global__ void scan_block_kernel(const int* __restrict__ cnt,
                                  int* __restrict__ offs,
                                  int* __restrict__ bsums) {
    __shared__ int tmp[256];
    int b = blockIdx.x, i = threadIdx.x, idx = b * 256 + i;
    int v = (idx < NN) ? cnt[idx] : 0;
    tmp[i] = v;
    __syncthreads();
    #pragma unroll
    for (int off = 1; off < 256; off <<= 1) {
        int t2 = (i >= off) ? tmp[i - off] : 0;
        __syncthreads();
        tmp[i] += t2;
        __syncthreads();
    }
    if (idx < NN) offs[idx] = tmp[i] - v;
    if (i == 255) bsums[b] = tmp[255];
}

__global__ void scan_sums_kernel(int* __restrict__ bsums) {
    __shared__ int tmp[512];
    int i = threadIdx.x;
    int v = (i < NB1) ? bsums[i] : 0;
    tmp[i] = v;
    __syncthreads();
    #pragma unroll
    for (int off = 1; off < 512; off <<= 1) {
        int t2 = (i >= off) ? tmp[i - off] : 0;
        __syncthreads();
        tmp[i] += t2;
        __syncthreads();
    }
    if (i < NB1) bsums[i] = tmp[i] - v;
}

__global__ void scan_add_kernel(int* __restrict__ offs,
                                const int* __restrict__ bsums,
                                int* __restrict__ cursor) {
    int b = blockIdx.x, idx = b * 256 + threadIdx.x;
    if (idx < NN) {
        int o = offs[idx] + bsums[b];
        offs[idx] = o;
        cursor[idx] = o;
    }
}

__global__ void scatter_kernel(const int* __restrict__ ei,
                               int* __restrict__ cursor,
                               int4* __restrict__ sSDE) {
    int e = blockIdx.x * 256 + threadIdx.x;   // grid 6250 x 256 == NE
    int src = ei[e], dst = ei[NE + e];
    int pos = atomicAdd(&cursor[dst], 1);
    int4 v; v.x = src; v.y = dst; v.z = e; v.w = 0;
    sSDE[pos] = v;
}

// ---- y12: yc[node] = [x@W1a | x@W1b] in bf16 (transposed MFMA) ---------
__global__ __launch_bounds__(256) void y12_kernel(
    const unsigned short* __restrict__ xb,
    const unsigned short* __restrict__ W1abT,
    unsigned short* __restrict__ yc) {
    __shared__ unsigned short sW[128 * KS];   // 18432 B
    int t = threadIdx.x;
    {
        const uint4* wv = (const uint4*)W1abT;
        uint4* sv = (uint4*)sW;
        for (int i = t; i < 128 * KS * 2 / 16; i += 256) sv[i] = wv[i];
    }
    __syncthreads();

    int lane = t & 63, w = t >> 6;
    int m = lane & 15, q = lane >> 4;
    int n0 = blockIdx.x * 64;
    int node = n0 + w * 16 + m;               // this lane's node (B-operand col)
    int nclamp = (node < NN) ? node : (NN - 1);

    floatx4 acc[8];
    #pragma unroll
    for (int i = 0; i < 8; i++) acc[i] = (floatx4){0.f, 0.f, 0.f, 0.f};
    #pragma unroll
    for (int kt = 0; kt < 2; kt++) {
        short8 bfr = *(const short8*)(xb + (size_t)nclamp * H + kt * 32 + q * 8);
        #pragma unroll
        for (int tt = 0; tt < 8; tt++) {
            short8 afr = *(const short8*)(sW + (tt * 16 + m) * KS + kt * 32 + q * 8);
            acc[tt] = __builtin_amdgcn_mfma_f32_16x16x32_bf16(afr, bfr, acc[tt], 0, 0, 0);
        }
    }
    // C' = y^T: lane holds node=node, channels tt*16+q*4+r (contiguous)
    if (node < NN) {
        #pragma unroll
        for (int tt = 0; tt < 8; tt++) {
            uint2 o;
            o.x = cvt_pk_bf16(acc[tt][0], acc[tt][1]);
            o.y = cvt_pk_bf16(acc[tt][2], acc[tt][3]);
            *(uint2*)(yc + (size_t)node * 128 + tt * 16 + q * 4) = o;
        }
    }
}

// ---- edge: h = silu(y1[src]+y2[dst]+ea@W1c+b1); m = silu(h@W2+b2); agg --
// All MFMAs transposed: weights as A, per-edge data as B -> lane owns one
// edge (col=m) and contiguous channels (rows) -> vector epilogues.
__global__ __launch_bounds__(256, 5) void edge_kernel(
    const unsigned short* __restrict__ yc,
    const float* __restrict__ ea,
    const int4* __restrict__ sSDE,
    const unsigned short* __restrict__ W1cT,
    const unsigned short* __restrict__ W2T,
    const float* __restrict__ b2,
    float* __restrict__ agg) {
    __shared__ float sY[64 * YS];            // 17408 B (aliased as sM later)
    __shared__ unsigned short sH[64 * KS];   // 9216 B
    __shared__ int sDst[64];
    __shared__ int sEid[64];
    float* sM = sY;

    int t = threadIdx.x;
    int lane = t & 63, w = t >> 6;
    int m = lane & 15, q = lane >> 4;

    // weight fragments (A-operands). Same addresses as B-pack layout.
    short8 w1c[4], w2f[2][4];
    #pragma unroll
    for (int tt = 0; tt < 4; tt++)
        w1c[tt] = *(const short8*)(W1cT + (tt * 16 + m) * 32 + q * 8);
    #pragma unroll
    for (int kt = 0; kt < 2; kt++)
        #pragma unroll
        for (int tt = 0; tt < 4; tt++)
            w2f[kt][tt] = *(const short8*)(W2T + (tt * 16 + m) * KS + kt * 32 + q * 8);

    // stage ysum = y1[src] + y2[dst] (fp32, vectorized) — 4 threads/edge
    {
        int eL = t >> 2, sub = t & 3;
        int gi = blockIdx.x * 64 + eL;
        int4 sde = sSDE[gi];
        if (sub == 0) { sDst[eL] = sde.y; sEid[eL] = sde.z; }
        const unsigned short* ys = yc + (size_t)sde.x * 128 + sub * 16;
        const unsigned short* yd = yc + (size_t)sde.y * 128 + 64 + sub * 16;
        short8 a0 = *(const short8*)(ys);
        short8 a1 = *(const short8*)(ys + 8);
        short8 d0 = *(const short8*)(yd);
        short8 d1 = *(const short8*)(yd + 8);
        float tmpv[16];
        #pragma unroll
        for (int j = 0; j < 8; j++) {
            tmpv[j]     = bf2f((unsigned short)a0[j]) + bf2f((unsigned short)d0[j]);
            tmpv[8 + j] = bf2f((unsigned short)a1[j]) + bf2f((unsigned short)d1[j]);
        }
        float4* o = (float4*)(sY + eL * YS + sub * 16);
        #pragma unroll
        for (int j = 0; j < 4; j++) o[j] = ((const float4*)tmpv)[j];
    }
    __syncthreads();

    int E = w * 16 + m;          // this lane's edge row within the 64-tile
    int e = sEid[E];

    // GEMM1 (K=32): C1' = (ea@W1c + b1)^T ; ea as B-operand, bias via 1.0
    short8 bf1 = {0, 0, 0, 0, 0, 0, 0, 0};
    if (q < 2) {
        const float4* p = (const float4*)(ea + (size_t)e * ED + q * 8);
        float4 v0 = p[0], v1 = p[1];
        union { unsigned u[4]; short8 s; } ub;
        ub.u[0] = cvt_pk_bf16(v0.x, v0.y);
        ub.u[1] = cvt_pk_bf16(v0.z, v0.w);
        ub.u[2] = cvt_pk_bf16(v1.x, v1.y);
        ub.u[3] = cvt_pk_bf16(v1.z, v1.w);
        bf1 = ub.s;
    } else if (q == 2) {
        bf1[0] = (short)0x3F80;   // k=16 -> multiplies b1 row
    }
    floatx4 acc[4];
    #pragma unroll
    for (int i = 0; i < 4; i++) acc[i] = (floatx4){0.f, 0.f, 0.f, 0.f};
    #pragma unroll
    for (int tt = 0; tt < 4; tt++)
        acc[tt] = __builtin_amdgcn_mfma_f32_16x16x32_bf16(w1c[tt], bf1, acc[tt], 0, 0, 0);

    // epi1: lane owns edge E, channels tt*16+q*4..+3 -> vector LDS ops
    #pragma unroll
    for (int tt = 0; tt < 4; tt++) {
        float4 ys4 = *(const float4*)(sY + E * YS + tt * 16 + q * 4);
        uint2 hp;
        hp.x = cvt_pk_bf16(silu(acc[tt][0] + ys4.x), silu(acc[tt][1] + ys4.y));
        hp.y = cvt_pk_bf16(silu(acc[tt][2] + ys4.z), silu(acc[tt][3] + ys4.w));
        *(uint2*)(sH + E * KS + tt * 16 + q * 4) = hp;
    }
    __syncthreads();   // sH visible; all sY reads done (sM aliasing safe)

    // GEMM2: C2' = (h@W2)^T ; h fragment as B-operand (same read as before)
    floatx4 acc2[4];
    #pragma unroll
    for (int i = 0; i < 4; i++) acc2[i] = (floatx4){0.f, 0.f, 0.f, 0.f};
    #pragma unroll
    for (int kt = 0; kt < 2; kt++) {
        short8 hfr = *(const short8*)(sH + E * KS + kt * 32 + q * 8);
        #pragma unroll
        for (int tt = 0; tt < 4; tt++)
            acc2[tt] = __builtin_amdgcn_mfma_f32_16x16x32_bf16(w2f[kt][tt], hfr, acc2[tt], 0, 0, 0);
    }

    // epi2: messages -> sM (fp32, vector stores; aliases sY)
    #pragma unroll
    for (int tt = 0; tt < 4; tt++) {
        float4 bb = *(const float4*)(b2 + tt * 16 + q * 4);
        float4 mv;
        mv.x = silu(acc2[tt][0] + bb.x);
        mv.y = silu(acc2[tt][1] + bb.y);
        mv.z = silu(acc2[tt][2] + bb.z);
        mv.w = silu(acc2[tt][3] + bb.w);
        *(float4*)(sM + E * YS + tt * 16 + q * 4) = mv;
    }
    __syncthreads();

    // segment-reduce: wave w reduces rows [w*16, w*16+16), lane = column
    {
        int c = lane;
        float s = 0.f;
        int cur = sDst[w * 16];
        #pragma unroll
        for (int r = 0; r < 16; r++) {
            int rr = w * 16 + r;
            int d = sDst[rr];
            if (d != cur) {
                atomicAdd(&agg[(size_t)cur * H + c], s);
                s = 0.f;
                cur = d;
            }
            s += sM[rr * YS + c];
        }
        atomicAdd(&agg[(size_t)cur * H + c], s);
    }
}

// ---- node MLP (transposed MFMA) ----------------------------------------
__global__ __launch_bounds__(256) void node_kernel(
    const unsigned short* __restrict__ xb,
    const float* __restrict__ agg,
    const unsigned short* __restrict__ W3T,
    const float* __restrict__ b3,
    float* __restrict__ out) {
    __shared__ unsigned short sW3[64 * K3S];
    __shared__ unsigned short sA[64 * K3S];

    int t = threadIdx.x;
    int n0 = blockIdx.x * 64;

    {
        const uint4* wv = (const uint4*)W3T;
        uint4* sv = (uint4*)sW3;
        for (int i = t; i < 64 * K3S * 2 / 16; i += 256) sv[i] = wv[i];
    }
    {
        int nL = t >> 2, sub = t & 3;
        int node = n0 + nL;
        uint4* arow = (uint4*)(sA + nL * K3S);
        if (node < NN) {
            const uint4* xs = (const uint4*)(xb + (size_t)node * H);
            arow[sub * 2]     = xs[sub * 2];
            arow[sub * 2 + 1] = xs[sub * 2 + 1];
            const float4* av = (const float4*)(agg + (size_t)node * H);
            unsigned tmp[8];
            #pragma unroll
            for (int j = 0; j < 4; j++) {
                float4 v = av[sub * 4 + j];
                tmp[j * 2 + 0] = cvt_pk_bf16(v.x, v.y);
                tmp[j * 2 + 1] = cvt_pk_bf16(v.z, v.w);
            }
            uint4* drow = (uint4*)(sA + nL * K3S + 64 + sub * 16);
            drow[0] = ((const uint4*)tmp)[0];
            drow[1] = ((const uint4*)tmp)[1];
        } else {
            uint4 z = {0, 0, 0, 0};
            arow[sub * 2] = z; arow[sub * 2 + 1] = z;
            uint4* drow = (uint4*)(sA + nL * K3S + 64 + sub * 16);
            drow[0] = z; drow[1] = z;
        }
    }
    __syncthreads();

    int w = t >> 6, lane = t & 63;
    int m = lane & 15, q = lane >> 4;
    int node = n0 + w * 16 + m;   // this lane's node (B-operand col)

    floatx4 acc[4];
    #pragma unroll
    for (int i = 0; i < 4; i++) acc[i] = (floatx4){0.f, 0.f, 0.f, 0.f};
    #pragma unroll
    for (int kt = 0; kt < 4; kt++) {
        short8 bfr = *(const short8*)(sA + (w * 16 + m) * K3S + kt * 32 + q * 8);
        #pragma unroll
        for (int tt = 0; tt < 4; tt++) {
            short8 afr = *(const short8*)(sW3 + (tt * 16 + m) * K3S + kt * 32 + q * 8);
            acc[tt] = __builtin_amdgcn_mfma_f32_16x16x32_bf16(afr, bfr, acc[tt], 0, 0, 0);
        }
    }
    if (node < NN) {
        #pragma unroll
        for (int tt = 0; tt < 4; tt++) {
            float4 bb = *(const float4*)(b3 + tt * 16 + q * 4);
            float4 ov;
            ov.x = silu(acc[tt][0] + bb.x);
            ov.y = silu(acc[tt][1] + bb.y);
            ov.z = silu(acc[tt][2] + bb.z);
            ov.w = silu(acc[tt][3] + bb.w);
            *(float4*)(out + (size_t)node * H + tt * 16 + q * 4) = ov;
        }
    }
}

static inline size_t align256(size_t x) { return (x + 255) & ~(size_t)255; }

extern "C" void kernel_launch(void* const* d_in, const int* in_sizes, int n_in,
                              void* d_out, int out_size, void* d_ws, size_t ws_size,
                              hipStream_t stream) {
    const float* x  = (const float*)d_in[0];
    const int*   ei = (const int*)d_in[1];
    const float* ea = (const float*)d_in[2];
    const float* W1 = (const float*)d_in[3];
    const float* b1 = (const float*)d_in[4];
    const float* W2 = (const float*)d_in[5];
    const float* b2 = (const float*)d_in[6];
    const float* W3 = (const float*)d_in[7];
    const float* b3 = (const float*)d_in[8];
    float* out = (float*)d_out;

    char* ws = (char*)d_ws;
    size_t o = 0;
    float* agg = (float*)(ws + o);                    o = align256(o + (size_t)NN * H * 4);
    unsigned short* xb = (unsigned short*)(ws + o);   o = align256(o + (size_t)NN * H * 2);
    unsigned short* yc = (unsigned short*)(ws + o);   o = align256(o + (size_t)NN * 128 * 2);
    unsigned short* W1abT = (unsigned short*)(ws + o); o = align256(o + 128 * KS * 2);
    unsigned short* W1cT = (unsigned short*)(ws + o); o = align256(o + 64 * 32 * 2);
    unsigned short* W2T = (unsigned short*)(ws + o);  o = align256(o + 64 * KS * 2);
    unsigned short* W3T = (unsigned short*)(ws + o);  o = align256(o + 64 * K3S * 2);
    int* offs = (int*)(ws + o);                       o = align256(o + (size_t)NN * 4);
    int* bsums = (int*)(ws + o);                      o = align256(o + NB1 * 4);
    int* cnt = (int*)(ws + o);                        o = align256(o + (size_t)NN * 4);
    int4* sSDE = (int4*)(ws + o);                     o = align256(o + (size_t)NE * 16);

    int* cursor = cnt;

    hipMemsetAsync(agg, 0, (size_t)NN * H * sizeof(float), stream);
    hipMemsetAsync(cnt, 0, (size_t)NN * sizeof(int), stream);
    prep_kernel<<<2048, 256, 0, stream>>>(x, W1, b1, W2, W3, ei, xb, W1abT, W1cT, W2T, W3T, cnt);
    scan_block_kernel<<<NB1, 256, 0, stream>>>(cnt, offs, bsums);
    scan_sums_kernel<<<1, 512, 0, stream>>>(bsums);
    scan_add_kernel<<<NB1, 256, 0, stream>>>(offs, bsums, cursor);
    scatter_kernel<<<NE / 256, 256, 0, stream>>>(ei, cursor, sSDE);
    y12_kernel<<<NNB, 256, 0, stream>>>(xb, W1abT, yc);
    edge_kernel<<<NT, 256, 0, stream>>>(yc, ea, sSDE, W1cT, W2T, b2, agg);
    node_kernel<<<NNB, 256, 0, stream>>>(xb, agg, W3T, b3, out);
}

// Round 3
// 521.845 us; speedup vs baseline: 1.0490x; 1.0163x over previous
//
#include <hip/hip_runtime.h>
#include <hip/hip_bf16.h>

#define NE 1600000
#define NN 100000
#define H 64
#define ED 16
#define NT (NE / 64)        // 25000 edge tiles
#define NB1 391             // ceil(NN/256) scan blocks
#define NNB 1563            // ceil(NN/64) node tiles

#define KS  72    // bf16 K-stride for K=64 packs (W1ab, W2, sH)
#define K3S 136   // bf16 row stride, node GEMM (K=128)
#define YS  68    // fp32 row stride for message buffer

typedef __attribute__((ext_vector_type(8))) short short8;
typedef __attribute__((ext_vector_type(4))) float floatx4;

__device__ __forceinline__ unsigned short f2bf(float f) {
    union { float f; unsigned u; } v; v.f = f;
    unsigned r = v.u + 0x7fff + ((v.u >> 16) & 1);
    return (unsigned short)(r >> 16);
}

__device__ __forceinline__ float bf2f(unsigned short u) {
    union { unsigned u; float f; } v; v.u = ((unsigned)u) << 16;
    return v.f;
}

// v_cvt_pk_bf16_f32: packs 2 f32 -> 2 bf16 (RNE) in ONE VALU op.
__device__ __forceinline__ unsigned cvt_pk_bf16(float lo, float hi) {
    unsigned r;
    asm("v_cvt_pk_bf16_f32 %0, %1, %2" : "=v"(r) : "v"(lo), "v"(hi));
    return r;
}

// silu via fast rcp (1 instr) instead of IEEE divide (~10 instr)
__device__ __forceinline__ float silu(float x) {
    return x * __builtin_amdgcn_rcpf(1.0f + __expf(-x));
}

// ---- prep: x->bf16, weight packs, histogram (fused) --------------------
__global__ void prep_kernel(const float* __restrict__ x,
                            const float* __restrict__ W1,
                            const float* __restrict__ b1,
                            const float* __restrict__ W2,
                            const float* __restrict__ W3,
                            const int* __restrict__ ei,
                            unsigned short* __restrict__ xb,
                            unsigned short* __restrict__ W1abT,
                            unsigned short* __restrict__ W1cT,
                            unsigned short* __restrict__ W2T,
                            unsigned short* __restrict__ W3T,
                            int* __restrict__ cnt) {
    int tid = blockIdx.x * blockDim.x + threadIdx.x;
    int nt = gridDim.x * blockDim.x;
    const float4* xv = (const float4*)x;
    uint2* xbv = (uint2*)xb;
    for (int i = tid; i < NN * H / 4; i += nt) {
        float4 v = xv[i];
        uint2 o;
        o.x = cvt_pk_bf16(v.x, v.y);
        o.y = cvt_pk_bf16(v.z, v.w);
        xbv[i] = o;
    }
    // W1abT[n][k]: n<64 -> W1[k][n] (x_src part); n in 64..127 -> W1[64+k][n-64]
    for (int i = tid; i < 128 * KS; i += nt) {
        int n = i / KS, k = i % KS;
        W1abT[i] = (k < 64) ? f2bf(W1[(size_t)((n < 64) ? k : 64 + k) * 64 + (n & 63)])
                            : (unsigned short)0;
    }
    // W1cT[n][k]: k<16 -> W1[128+k][n]; k==16 -> b1[n] (bias slot); else 0
    for (int i = tid; i < 64 * 32; i += nt) {
        int n = i / 32, k = i % 32;
        unsigned short v = 0;
        if (k < 16) v = f2bf(W1[(size_t)(128 + k) * 64 + n]);
        else if (k == 16) v = f2bf(b1[n]);
        W1cT[i] = v;
    }
    for (int i = tid; i < 64 * KS; i += nt) {
        int n = i / KS, k = i % KS;
        W2T[i] = (k < 64) ? f2bf(W2[k * 64 + n]) : (unsigned short)0;
    }
    for (int i = tid; i < 64 * K3S; i += nt) {
        int n = i / K3S, k = i % K3S;
        W3T[i] = (k < 128) ? f2bf(W3[k * 64 + n]) : (unsigned short)0;
    }
    // histogram of dst
    for (int e = tid; e < NE; e += nt) {
        atomicAdd(&cnt[ei[NE + e]], 1);
    }
}

// ---- counting-sort scan ------------------------------------------------
__global__ void scan_block_kernel(const int* __restrict__ cnt,
                                  int* __restrict__ offs,
                                  int* __restrict__ bsums) {
    __shared__ int tmp[256];
    int b = blockIdx.x, i = threadIdx.x, idx = b * 256 + i;
    int v = (idx < NN) ? cnt[idx] : 0;
    tmp[i] = v;
    __syncthreads();
    #pragma unroll
    for (int off = 1; off < 256; off <<= 1) {
        int t2 = (i >= off) ? tmp[i - off] : 0;
        __syncthreads();
        tmp[i] += t2;
        __syncthreads();
    }
    if (idx < NN) offs[idx] = tmp[i] - v;
    if (i == 255) bsums[b] = tmp[255];
}

__global__ void scan_sums_kernel(int* __restrict__ bsums) {
    __shared__ int tmp[512];
    int i = threadIdx.x;
    int v = (i < NB1) ? bsums[i] : 0;
    tmp[i] = v;
    __syncthreads();
    #pragma unroll
    for (int off = 1; off < 512; off <<= 1) {
        int t2 = (i >= off) ? tmp[i - off] : 0;
        __syncthreads();
        tmp[i] += t2;
        __syncthreads();
    }
    if (i < NB1) bsums[i] = tmp[i] - v;
}

__global__ void scan_add_kernel(int* __restrict__ offs,
                                const int* __restrict__ bsums,
                                int* __restrict__ cursor) {
    int b = blockIdx.x, idx = b * 256 + threadIdx.x;
    if (idx < NN) {
        int o = offs[idx] + bsums[b];
        offs[idx] = o;
        cursor[idx] = o;
    }
}

__global__ void scatter_kernel(const int* __restrict__ ei,
                               int* __restrict__ cursor,
                               int4* __restrict__ sSDE) {
    int e = blockIdx.x * 256 + threadIdx.x;   // grid 6250 x 256 == NE
    int src = ei[e], dst = ei[NE + e];
    int pos = atomicAdd(&cursor[dst], 1);
    int4 v; v.x = src; v.y = dst; v.z = e; v.w = 0;
    sSDE[pos] = v;
}

// ---- y12: yc[node] = [x@W1a | x@W1b] in bf16 (transposed MFMA) ---------
__global__ __launch_bounds__(256) void y12_kernel(
    const unsigned short* __restrict__ xb,
    const unsigned short* __restrict__ W1abT,
    unsigned short* __restrict__ yc) {
    __shared__ unsigned short sW[128 * KS];   // 18432 B
    int t = threadIdx.x;
    {
        const uint4* wv = (const uint4*)W1abT;
        uint4* sv = (uint4*)sW;
        for (int i = t; i < 128 * KS * 2 / 16; i += 256) sv[i] = wv[i];
    }
    __syncthreads();

    int lane = t & 63, w = t >> 6;
    int m = lane & 15, q = lane >> 4;
    int n0 = blockIdx.x * 64;
    int node = n0 + w * 16 + m;               // this lane's node (B-operand col)
    int nclamp = (node < NN) ? node : (NN - 1);

    floatx4 acc[8];
    #pragma unroll
    for (int i = 0; i < 8; i++) acc[i] = (floatx4){0.f, 0.f, 0.f, 0.f};
    #pragma unroll
    for (int kt = 0; kt < 2; kt++) {
        short8 bfr = *(const short8*)(xb + (size_t)nclamp * H + kt * 32 + q * 8);
        #pragma unroll
        for (int tt = 0; tt < 8; tt++) {
            short8 afr = *(const short8*)(sW + (tt * 16 + m) * KS + kt * 32 + q * 8);
            acc[tt] = __builtin_amdgcn_mfma_f32_16x16x32_bf16(afr, bfr, acc[tt], 0, 0, 0);
        }
    }
    // C' = y^T: lane holds node=node, channels tt*16+q*4+r (contiguous)
    if (node < NN) {
        #pragma unroll
        for (int tt = 0; tt < 8; tt++) {
            uint2 o;
            o.x = cvt_pk_bf16(acc[tt][0], acc[tt][1]);
            o.y = cvt_pk_bf16(acc[tt][2], acc[tt][3]);
            *(uint2*)(yc + (size_t)node * 128 + tt * 16 + q * 4) = o;
        }
    }
}

// ---- edge: h = silu(y1[src]+y2[dst]+ea@W1c+b1); m = silu(h@W2+b2); agg --
// Barrier-free: y1/y2 are folded into GEMM1 via identity A-fragments, so
// every remaining LDS buffer (sH, sM, sDst) is accessed ONLY by the wave
// that owns rows [w*16, w*16+16). DS ops process in-order per wave; the
// compiler's lgkmcnt waits (same-array aliasing) give cross-lane
// visibility without any __syncthreads.
__global__ __launch_bounds__(256, 6) void edge_kernel(
    const unsigned short* __restrict__ yc,
    const float* __restrict__ ea,
    const int4* __restrict__ sSDE,
    const unsigned short* __restrict__ W1cT,
    const unsigned short* __restrict__ W2T,
    const float* __restrict__ b2,
    float* __restrict__ agg) {
    __shared__ float sM[64 * YS];            // 17408 B (messages, fp32)
    __shared__ unsigned short sH[64 * KS];   // 9216 B
    __shared__ int sDst[64];

    int t = threadIdx.x;
    int lane = t & 63, w = t >> 6;
    int m = lane & 15, q = lane >> 4;
    int E = w * 16 + m;          // this lane's edge row within the 64-tile

    int4 sde = sSDE[(size_t)blockIdx.x * 64 + E];
    if (q == 0) sDst[E] = sde.y;
    int e = sde.z;

    // identity A-fragments (2 distinct; even/odd tt repeat the pattern).
    // A_tile[r][kl] = delta(kl == (tt&1)*16 + r): lane (m,q) holds the 1.0
    // at j = m&7 iff q == ((tt&1)<<1) | (m>>3). Built with selects (no
    // runtime vector indexing -> stays in registers).
    union uf { unsigned u[4]; short8 s; };
    uf idA, idB;
    {
        unsigned val = (m & 1) ? 0x3F800000u : 0x00003F80u;
        int wsel = (m >> 1) & 3;
        bool gA = (q == (m >> 3));
        bool gB = (q == 2 + (m >> 3));
        #pragma unroll
        for (int i = 0; i < 4; i++) {
            idA.u[i] = (gA && wsel == i) ? val : 0u;
            idB.u[i] = (gB && wsel == i) ? val : 0u;
        }
    }

    // B-fragments: scattered 16B gathers of y1[src], y2[dst] (bf16)
    short8 y1f0 = *(const short8*)(yc + (size_t)sde.x * 128 + q * 8);
    short8 y1f1 = *(const short8*)(yc + (size_t)sde.x * 128 + 32 + q * 8);
    short8 y2f0 = *(const short8*)(yc + (size_t)sde.y * 128 + 64 + q * 8);
    short8 y2f1 = *(const short8*)(yc + (size_t)sde.y * 128 + 96 + q * 8);

    // GEMM1 B-operand from ea (K=32 with bias slot at k=16)
    short8 bf1 = {0, 0, 0, 0, 0, 0, 0, 0};
    if (q < 2) {
        const float4* p = (const float4*)(ea + (size_t)e * ED + q * 8);
        float4 v0 = p[0], v1 = p[1];
        union { unsigned u[4]; short8 s; } ub;
        ub.u[0] = cvt_pk_bf16(v0.x, v0.y);
        ub.u[1] = cvt_pk_bf16(v0.z, v0.w);
        ub.u[2] = cvt_pk_bf16(v1.x, v1.y);
        ub.u[3] = cvt_pk_bf16(v1.z, v1.w);
        bf1 = ub.s;
    } else if (q == 2) {
        bf1[0] = (short)0x3F80;   // k=16 -> multiplies b1 row
    }

    // GEMM1: pre = ea@W1c + b1 + y1[src] + y2[dst], all inside MFMA accs
    floatx4 acc[4];
    #pragma unroll
    for (int tt = 0; tt < 4; tt++) {
        short8 w1c = *(const short8*)(W1cT + (tt * 16 + m) * 32 + q * 8);
        floatx4 a = (floatx4){0.f, 0.f, 0.f, 0.f};
        a = __builtin_amdgcn_mfma_f32_16x16x32_bf16(w1c, bf1, a, 0, 0, 0);
        short8 idt = (tt & 1) ? idB.s : idA.s;
        a = __builtin_amdgcn_mfma_f32_16x16x32_bf16(idt, (tt >> 1) ? y1f1 : y1f0, a, 0, 0, 0);
        a = __builtin_amdgcn_mfma_f32_16x16x32_bf16(idt, (tt >> 1) ? y2f1 : y2f0, a, 0, 0, 0);
        acc[tt] = a;
    }

    // epi1: h = silu(pre) -> bf16 -> sH (wave-private rows)
    #pragma unroll
    for (int tt = 0; tt < 4; tt++) {
        uint2 hp;
        hp.x = cvt_pk_bf16(silu(acc[tt][0]), silu(acc[tt][1]));
        hp.y = cvt_pk_bf16(silu(acc[tt][2]), silu(acc[tt][3]));
        *(uint2*)(sH + E * KS + tt * 16 + q * 4) = hp;
    }

    // GEMM2: C2' = (h@W2)^T ; h fragment as B-operand (intra-wave sH read)
    floatx4 acc2[4];
    #pragma unroll
    for (int i = 0; i < 4; i++) acc2[i] = (floatx4){0.f, 0.f, 0.f, 0.f};
    #pragma unroll
    for (int kt = 0; kt < 2; kt++) {
        short8 hfr = *(const short8*)(sH + E * KS + kt * 32 + q * 8);
        #pragma unroll
        for (int tt = 0; tt < 4; tt++) {
            short8 w2 = *(const short8*)(W2T + (tt * 16 + m) * KS + kt * 32 + q * 8);
            acc2[tt] = __builtin_amdgcn_mfma_f32_16x16x32_bf16(w2, hfr, acc2[tt], 0, 0, 0);
        }
    }

    // epi2: messages -> sM (fp32, wave-private rows)
    #pragma unroll
    for (int tt = 0; tt < 4; tt++) {
        float4 bb = *(const float4*)(b2 + tt * 16 + q * 4);
        float4 mv;
        mv.x = silu(acc2[tt][0] + bb.x);
        mv.y = silu(acc2[tt][1] + bb.y);
        mv.z = silu(acc2[tt][2] + bb.z);
        mv.w = silu(acc2[tt][3] + bb.w);
        *(float4*)(sM + E * YS + tt * 16 + q * 4) = mv;
    }

    // segment-reduce: wave w reduces its own rows [w*16, w*16+16), lane=col
    {
        int c = lane;
        float s = 0.f;
        int cur = sDst[w * 16];
        #pragma unroll
        for (int r = 0; r < 16; r++) {
            int rr = w * 16 + r;
            int d = sDst[rr];
            if (d != cur) {
                atomicAdd(&agg[(size_t)cur * H + c], s);
                s = 0.f;
                cur = d;
            }
            s += sM[rr * YS + c];
        }
        atomicAdd(&agg[(size_t)cur * H + c], s);
    }
}

// ---- node MLP (transposed MFMA) ----------------------------------------
__global__ __launch_bounds__(256) void node_kernel(
    const unsigned short* __restrict__ xb,
    const float* __restrict__ agg,
    const unsigned short* __restrict__ W3T,
    const float* __restrict__ b3,
    float* __restrict__ out) {
    __shared__ unsigned short sW3[64 * K3S];
    __shared__ unsigned short sA[64 * K3S];

    int t = threadIdx.x;
    int n0 = blockIdx.x * 64;

    {
        const uint4* wv = (const uint4*)W3T;
        uint4* sv = (uint4*)sW3;
        for (int i = t; i < 64 * K3S * 2 / 16; i += 256) sv[i] = wv[i];
    }
    {
        int nL = t >> 2, sub = t & 3;
        int node = n0 + nL;
        uint4* arow = (uint4*)(sA + nL * K3S);
        if (node < NN) {
            const uint4* xs = (const uint4*)(xb + (size_t)node * H);
            arow[sub * 2]     = xs[sub * 2];
            arow[sub * 2 + 1] = xs[sub * 2 + 1];
            const float4* av = (const float4*)(agg + (size_t)node * H);
            unsigned tmp[8];
            #pragma unroll
            for (int j = 0; j < 4; j++) {
                float4 v = av[sub * 4 + j];
                tmp[j * 2 + 0] = cvt_pk_bf16(v.x, v.y);
                tmp[j * 2 + 1] = cvt_pk_bf16(v.z, v.w);
            }
            uint4* drow = (uint4*)(sA + nL * K3S + 64 + sub * 16);
            drow[0] = ((const uint4*)tmp)[0];
            drow[1] = ((const uint4*)tmp)[1];
        } else {
            uint4 z = {0, 0, 0, 0};
            arow[sub * 2] = z; arow[sub * 2 + 1] = z;
            uint4* drow = (uint4*)(sA + nL * K3S + 64 + sub * 16);
            drow[0] = z; drow[1] = z;
        }
    }
    __syncthreads();

    int w = t >> 6, lane = t & 63;
    int m = lane & 15, q = lane >> 4;
    int node = n0 + w * 16 + m;   // this lane's node (B-operand col)

    floatx4 acc[4];
    #pragma unroll
    for (int i = 0; i < 4; i++) acc[i] = (floatx4){0.f, 0.f, 0.f, 0.f};
    #pragma unroll
    for (int kt = 0; kt < 4; kt++) {
        short8 bfr = *(const short8*)(sA + (w * 16 + m) * K3S + kt * 32 + q * 8);
        #pragma unroll
        for (int tt = 0; tt < 4; tt++) {
            short8 afr = *(const short8*)(sW3 + (tt * 16 + m) * K3S + kt * 32 + q * 8);
            acc[tt] = __builtin_amdgcn_mfma_f32_16x16x32_bf16(afr, bfr, acc[tt], 0, 0, 0);
        }
    }
    if (node < NN) {
        #pragma unroll
        for (int tt = 0; tt < 4; tt++) {
            float4 bb = *(const float4*)(b3 + tt * 16 + q * 4);
            float4 ov;
            ov.x = silu(acc[tt][0] + bb.x);
            ov.y = silu(acc[tt][1] + bb.y);
            ov.z = silu(acc[tt][2] + bb.z);
            ov.w = silu(acc[tt][3] + bb.w);
            *(float4*)(out + (size_t)node * H + tt * 16 + q * 4) = ov;
        }
    }
}

static inline size_t align256(size_t x) { return (x + 255) & ~(size_t)255; }

extern "C" void kernel_launch(void* const* d_in, const int* in_sizes, int n_in,
                              void* d_out, int out_size, void* d_ws, size_t ws_size,
                              hipStream_t stream) {
    const float* x  = (const float*)d_in[0];
    const int*   ei = (const int*)d_in[1];
    const float* ea = (const float*)d_in[2];
    const float* W1 = (const float*)d_in[3];
    const float* b1 = (const float*)d_in[4];
    const float* W2 = (const float*)d_in[5];
    const float* b2 = (const float*)d_in[6];
    const float* W3 = (const float*)d_in[7];
    const float* b3 = (const float*)d_in[8];
    float* out = (float*)d_out;

    char* ws = (char*)d_ws;
    size_t o = 0;
    float* agg = (float*)(ws + o);                    o = align256(o + (size_t)NN * H * 4);
    unsigned short* xb = (unsigned short*)(ws + o);   o = align256(o + (size_t)NN * H * 2);
    unsigned short* yc = (unsigned short*)(ws + o);   o = align256(o + (size_t)NN * 128 * 2);
    unsigned short* W1abT = (unsigned short*)(ws + o); o = align256(o + 128 * KS * 2);
    unsigned short* W1cT = (unsigned short*)(ws + o); o = align256(o + 64 * 32 * 2);
    unsigned short* W2T = (unsigned short*)(ws + o);  o = align256(o + 64 * KS * 2);
    unsigned short* W3T = (unsigned short*)(ws + o);  o = align256(o + 64 * K3S * 2);
    int* offs = (int*)(ws + o);                       o = align256(o + (size_t)NN * 4);
    int* bsums = (int*)(ws + o);                      o = align256(o + NB1 * 4);
    int* cnt = (int*)(ws + o);                        o = align256(o + (size_t)NN * 4);
    int4* sSDE = (int4*)(ws + o);                     o = align256(o + (size_t)NE * 16);

    int* cursor = cnt;

    hipMemsetAsync(agg, 0, (size_t)NN * H * sizeof(float), stream);
    hipMemsetAsync(cnt, 0, (size_t)NN * sizeof(int), stream);
    prep_kernel<<<2048, 256, 0, stream>>>(x, W1, b1, W2, W3, ei, xb, W1abT, W1cT, W2T, W3T, cnt);
    scan_block_kernel<<<NB1, 256, 0, stream>>>(cnt, offs, bsums);
    scan_sums_kernel<<<1, 512, 0, stream>>>(bsums);
    scan_add_kernel<<<NB1, 256, 0, stream>>>(offs, bsums, cursor);
    scatter_kernel<<<NE / 256, 256, 0, stream>>>(ei, cursor, sSDE);
    y12_kernel<<<NNB, 256, 0, stream>>>(xb, W1abT, yc);
    edge_kernel<<<NT, 256, 0, stream>>>(yc, ea, sSDE, W1cT, W2T, b2, agg);
    node_kernel<<<NNB, 256, 0, stream>>>(xb, agg, W3T, b3, out);
}

// Round 4
// 510.029 us; speedup vs baseline: 1.0733x; 1.0232x over previous
//
#include <hip/hip_runtime.h>
#include <hip/hip_bf16.h>

#define NE 1600000
#define NN 100000
#define H 64
#define ED 16
#define NT (NE / 64)        // 25000 edge tiles
#define NB1 391             // ceil(NN/256) scan blocks
#define NNB 1563            // ceil(NN/64) node tiles

#define KS  72    // bf16 K-stride for K=64 packs (W1ab, W2, sH rows)
#define K3S 136   // bf16 row stride, node GEMM (K=128)
#define YS  68    // fp32 row stride for message rows

typedef __attribute__((ext_vector_type(8))) short short8;
typedef __attribute__((ext_vector_type(4))) float floatx4;

__device__ __forceinline__ unsigned short f2bf(float f) {
    union { float f; unsigned u; } v; v.f = f;
    unsigned r = v.u + 0x7fff + ((v.u >> 16) & 1);
    return (unsigned short)(r >> 16);
}

__device__ __forceinline__ float bf2f(unsigned short u) {
    union { unsigned u; float f; } v; v.u = ((unsigned)u) << 16;
    return v.f;
}

// v_cvt_pk_bf16_f32: packs 2 f32 -> 2 bf16 (RNE) in ONE VALU op.
__device__ __forceinline__ unsigned cvt_pk_bf16(float lo, float hi) {
    unsigned r;
    asm("v_cvt_pk_bf16_f32 %0, %1, %2" : "=v"(r) : "v"(lo), "v"(hi));
    return r;
}

// silu via fast rcp (1 instr) instead of IEEE divide (~10 instr)
__device__ __forceinline__ float silu(float x) {
    return x * __builtin_amdgcn_rcpf(1.0f + __expf(-x));
}

// ---- prep: x->bf16, weight packs, histogram, agg zero (fused) ----------
__global__ void prep_kernel(const float* __restrict__ x,
                            const float* __restrict__ W1,
                            const float* __restrict__ b1,
                            const float* __restrict__ W2,
                            const float* __restrict__ W3,
                            const int* __restrict__ ei,
                            unsigned short* __restrict__ xb,
                            unsigned short* __restrict__ W1abT,
                            unsigned short* __restrict__ W1cT,
                            unsigned short* __restrict__ W2T,
                            unsigned short* __restrict__ W3T,
                            int* __restrict__ cnt,
                            float4* __restrict__ aggv) {
    int tid = blockIdx.x * blockDim.x + threadIdx.x;
    int nt = gridDim.x * blockDim.x;
    const float4* xv = (const float4*)x;
    uint2* xbv = (uint2*)xb;
    for (int i = tid; i < NN * H / 4; i += nt) {
        float4 v = xv[i];
        uint2 o;
        o.x = cvt_pk_bf16(v.x, v.y);
        o.y = cvt_pk_bf16(v.z, v.w);
        xbv[i] = o;
    }
    // agg zero (replaces hipMemsetAsync dispatch)
    {
        float4 z = {0.f, 0.f, 0.f, 0.f};
        for (int i = tid; i < NN * H / 4; i += nt) aggv[i] = z;
    }
    // W1abT[n][k]: n<64 -> W1[k][n] (x_src part); n in 64..127 -> W1[64+k][n-64]
    for (int i = tid; i < 128 * KS; i += nt) {
        int n = i / KS, k = i % KS;
        W1abT[i] = (k < 64) ? f2bf(W1[(size_t)((n < 64) ? k : 64 + k) * 64 + (n & 63)])
                            : (unsigned short)0;
    }
    // W1cT[n][k]: k<16 -> W1[128+k][n]; k==16 -> b1[n] (bias slot); else 0
    for (int i = tid; i < 64 * 32; i += nt) {
        int n = i / 32, k = i % 32;
        unsigned short v = 0;
        if (k < 16) v = f2bf(W1[(size_t)(128 + k) * 64 + n]);
        else if (k == 16) v = f2bf(b1[n]);
        W1cT[i] = v;
    }
    for (int i = tid; i < 64 * KS; i += nt) {
        int n = i / KS, k = i % KS;
        W2T[i] = (k < 64) ? f2bf(W2[k * 64 + n]) : (unsigned short)0;
    }
    for (int i = tid; i < 64 * K3S; i += nt) {
        int n = i / K3S, k = i % K3S;
        W3T[i] = (k < 128) ? f2bf(W3[k * 64 + n]) : (unsigned short)0;
    }
    // histogram of dst
    for (int e = tid; e < NE; e += nt) {
        atomicAdd(&cnt[ei[NE + e]], 1);
    }
}

// ---- counting-sort scan ------------------------------------------------
__global__ void scan_block_kernel(const int* __restrict__ cnt,
                                  int* __restrict__ offs,
                                  int* __restrict__ bsums) {
    __shared__ int tmp[256];
    int b = blockIdx.x, i = threadIdx.x, idx = b * 256 + i;
    int v = (idx < NN) ? cnt[idx] : 0;
    tmp[i] = v;
    __syncthreads();
    #pragma unroll
    for (int off = 1; off < 256; off <<= 1) {
        int t2 = (i >= off) ? tmp[i - off] : 0;
        __syncthreads();
        tmp[i] += t2;
        __syncthreads();
    }
    if (idx < NN) offs[idx] = tmp[i] - v;
    if (i == 255) bsums[b] = tmp[255];
}

__global__ void scan_sums_kernel(int* __restrict__ bsums) {
    __shared__ int tmp[512];
    int i = threadIdx.x;
    int v = (i < NB1) ? bsums[i] : 0;
    tmp[i] = v;
    __syncthreads();
    #pragma unroll
    for (int off = 1; off < 512; off <<= 1) {
        int t2 = (i >= off) ? tmp[i - off] : 0;
        __syncthreads();
        tmp[i] += t2;
        __syncthreads();
    }
    if (i < NB1) bsums[i] = tmp[i] - v;
}

__global__ void scan_add_kernel(int* __restrict__ offs,
                                const int* __restrict__ bsums,
                                int* __restrict__ cursor) {
    int b = blockIdx.x, idx = b * 256 + threadIdx.x;
    if (idx < NN) {
        int o = offs[idx] + bsums[b];
        offs[idx] = o;
        cursor[idx] = o;
    }
}

// packed sorted-edge record: src(17b) | dst(17b)<<17 | e(21b)<<34
__global__ void scatter_kernel(const int* __restrict__ ei,
                               int* __restrict__ cursor,
                               unsigned long long* __restrict__ sSDE) {
    int e = blockIdx.x * 256 + threadIdx.x;   // grid 6250 x 256 == NE
    int src = ei[e], dst = ei[NE + e];
    int pos = atomicAdd(&cursor[dst], 1);
    unsigned long long v = (unsigned long long)src
                         | ((unsigned long long)dst << 17)
                         | ((unsigned long long)e << 34);
    sSDE[pos] = v;
}

// ---- y12: yc[node] = [x@W1a | x@W1b] in bf16 (transposed MFMA) ---------
__global__ __launch_bounds__(256) void y12_kernel(
    const unsigned short* __restrict__ xb,
    const unsigned short* __restrict__ W1abT,
    unsigned short* __restrict__ yc) {
    __shared__ unsigned short sW[128 * KS];   // 18432 B
    int t = threadIdx.x;
    {
        const uint4* wv = (const uint4*)W1abT;
        uint4* sv = (uint4*)sW;
        for (int i = t; i < 128 * KS * 2 / 16; i += 256) sv[i] = wv[i];
    }
    __syncthreads();

    int lane = t & 63, w = t >> 6;
    int m = lane & 15, q = lane >> 4;
    int n0 = blockIdx.x * 64;
    int node = n0 + w * 16 + m;               // this lane's node (B-operand col)
    int nclamp = (node < NN) ? node : (NN - 1);

    floatx4 acc[8];
    #pragma unroll
    for (int i = 0; i < 8; i++) acc[i] = (floatx4){0.f, 0.f, 0.f, 0.f};
    #pragma unroll
    for (int kt = 0; kt < 2; kt++) {
        short8 bfr = *(const short8*)(xb + (size_t)nclamp * H + kt * 32 + q * 8);
        #pragma unroll
        for (int tt = 0; tt < 8; tt++) {
            short8 afr = *(const short8*)(sW + (tt * 16 + m) * KS + kt * 32 + q * 8);
            acc[tt] = __builtin_amdgcn_mfma_f32_16x16x32_bf16(afr, bfr, acc[tt], 0, 0, 0);
        }
    }
    // C' = y^T: lane holds node=node, channels tt*16+q*4+r (contiguous)
    if (node < NN) {
        #pragma unroll
        for (int tt = 0; tt < 8; tt++) {
            uint2 o;
            o.x = cvt_pk_bf16(acc[tt][0], acc[tt][1]);
            o.y = cvt_pk_bf16(acc[tt][2], acc[tt][3]);
            *(uint2*)(yc + (size_t)node * 128 + tt * 16 + q * 4) = o;
        }
    }
}

// ---- edge: h = silu(y1[src]+y2[dst]+ea@W1c+b1); m = silu(h@W2+b2); agg --
// Barrier-free + per-wave LDS slabs. Each wave owns a 4352 B slab holding
// its sH rows (bf16, 144 B/row) AND its sM rows (fp32, 272 B/row) aliased:
// lifetime order within the wave is epi1-write(sH) -> GEMM2-read(sH) ->
// epi2-write(sM) -> reduce-read(sM), and DS ops execute in-order per wave,
// so the alias is safe. LDS total 17664 B -> 8 blocks/CU (vs 27136 -> 6).
__global__ __launch_bounds__(256, 8) void edge_kernel(
    const unsigned short* __restrict__ yc,
    const float* __restrict__ ea,
    const unsigned long long* __restrict__ sSDE,
    const unsigned short* __restrict__ W1cT,
    const unsigned short* __restrict__ W2T,
    const float* __restrict__ b2,
    float* __restrict__ agg) {
    __shared__ float sWS[4][1088];            // 4 x 4352 B wave slabs
    __shared__ int sDst[64];

    int t = threadIdx.x;
    int lane = t & 63, w = t >> 6;
    int m = lane & 15, q = lane >> 4;
    int E = w * 16 + m;          // this lane's edge row within the 64-tile

    unsigned long long sde = sSDE[(size_t)blockIdx.x * 64 + E];
    int src = (int)(sde & 0x1FFFF);
    int dst = (int)((sde >> 17) & 0x1FFFF);
    int e   = (int)(sde >> 34);
    if (q == 0) sDst[E] = dst;

    // identity A-fragments (2 distinct; even/odd tt repeat the pattern).
    // A_tile[r][kl] = delta(kl == (tt&1)*16 + r): lane (m,q) holds the 1.0
    // at j = m&7 iff q == ((tt&1)<<1) | (m>>3).
    union uf { unsigned u[4]; short8 s; };
    uf idA, idB;
    {
        unsigned val = (m & 1) ? 0x3F800000u : 0x00003F80u;
        int wsel = (m >> 1) & 3;
        bool gA = (q == (m >> 3));
        bool gB = (q == 2 + (m >> 3));
        #pragma unroll
        for (int i = 0; i < 4; i++) {
            idA.u[i] = (gA && wsel == i) ? val : 0u;
            idB.u[i] = (gB && wsel == i) ? val : 0u;
        }
    }

    // B-fragments: scattered 16B gathers of y1[src], y2[dst] (bf16)
    short8 y1f0 = *(const short8*)(yc + (size_t)src * 128 + q * 8);
    short8 y1f1 = *(const short8*)(yc + (size_t)src * 128 + 32 + q * 8);
    short8 y2f0 = *(const short8*)(yc + (size_t)dst * 128 + 64 + q * 8);
    short8 y2f1 = *(const short8*)(yc + (size_t)dst * 128 + 96 + q * 8);

    // GEMM1 B-operand from ea (K=32 with bias slot at k=16)
    short8 bf1 = {0, 0, 0, 0, 0, 0, 0, 0};
    if (q < 2) {
        const float4* p = (const float4*)(ea + (size_t)e * ED + q * 8);
        float4 v0 = p[0], v1 = p[1];
        union { unsigned u[4]; short8 s; } ub;
        ub.u[0] = cvt_pk_bf16(v0.x, v0.y);
        ub.u[1] = cvt_pk_bf16(v0.z, v0.w);
        ub.u[2] = cvt_pk_bf16(v1.x, v1.y);
        ub.u[3] = cvt_pk_bf16(v1.z, v1.w);
        bf1 = ub.s;
    } else if (q == 2) {
        bf1[0] = (short)0x3F80;   // k=16 -> multiplies b1 row
    }

    // GEMM1: pre = ea@W1c + b1 + y1[src] + y2[dst], all inside MFMA accs
    floatx4 acc[4];
    #pragma unroll
    for (int tt = 0; tt < 4; tt++) {
        short8 w1c = *(const short8*)(W1cT + (tt * 16 + m) * 32 + q * 8);
        floatx4 a = (floatx4){0.f, 0.f, 0.f, 0.f};
        a = __builtin_amdgcn_mfma_f32_16x16x32_bf16(w1c, bf1, a, 0, 0, 0);
        short8 idt = (tt & 1) ? idB.s : idA.s;
        a = __builtin_amdgcn_mfma_f32_16x16x32_bf16(idt, (tt >> 1) ? y1f1 : y1f0, a, 0, 0, 0);
        a = __builtin_amdgcn_mfma_f32_16x16x32_bf16(idt, (tt >> 1) ? y2f1 : y2f0, a, 0, 0, 0);
        acc[tt] = a;
    }

    // epi1: h = silu(pre) -> bf16 -> sH rows in this wave's slab
    unsigned short* sHw = (unsigned short*)sWS[w];
    #pragma unroll
    for (int tt = 0; tt < 4; tt++) {
        uint2 hp;
        hp.x = cvt_pk_bf16(silu(acc[tt][0]), silu(acc[tt][1]));
        hp.y = cvt_pk_bf16(silu(acc[tt][2]), silu(acc[tt][3]));
        *(uint2*)(sHw + m * KS + tt * 16 + q * 4) = hp;
    }

    // GEMM2: C2' = (h@W2)^T ; h fragment as B-operand (intra-wave sH read)
    floatx4 acc2[4];
    #pragma unroll
    for (int i = 0; i < 4; i++) acc2[i] = (floatx4){0.f, 0.f, 0.f, 0.f};
    #pragma unroll
    for (int kt = 0; kt < 2; kt++) {
        short8 hfr = *(const short8*)(sHw + m * KS + kt * 32 + q * 8);
        #pragma unroll
        for (int tt = 0; tt < 4; tt++) {
            short8 w2 = *(const short8*)(W2T + (tt * 16 + m) * KS + kt * 32 + q * 8);
            acc2[tt] = __builtin_amdgcn_mfma_f32_16x16x32_bf16(w2, hfr, acc2[tt], 0, 0, 0);
        }
    }

    // epi2: messages -> sM rows in this wave's slab (aliases sH; all sH
    // reads by this wave completed above, DS in-order per wave)
    float* sMw = sWS[w];
    #pragma unroll
    for (int tt = 0; tt < 4; tt++) {
        float4 bb = *(const float4*)(b2 + tt * 16 + q * 4);
        float4 mv;
        mv.x = silu(acc2[tt][0] + bb.x);
        mv.y = silu(acc2[tt][1] + bb.y);
        mv.z = silu(acc2[tt][2] + bb.z);
        mv.w = silu(acc2[tt][3] + bb.w);
        *(float4*)(sMw + m * YS + tt * 16 + q * 4) = mv;
    }

    // segment-reduce: wave w reduces its own 16 rows, lane = column
    {
        int c = lane;
        float s = 0.f;
        int cur = sDst[w * 16];
        #pragma unroll
        for (int r = 0; r < 16; r++) {
            int d = sDst[w * 16 + r];
            if (d != cur) {
                atomicAdd(&agg[(size_t)cur * H + c], s);
                s = 0.f;
                cur = d;
            }
            s += sMw[r * YS + c];
        }
        atomicAdd(&agg[(size_t)cur * H + c], s);
    }
}

// ---- node MLP (transposed MFMA) ----------------------------------------
__global__ __launch_bounds__(256) void node_kernel(
    const unsigned short* __restrict__ xb,
    const float* __restrict__ agg,
    const unsigned short* __restrict__ W3T,
    const float* __restrict__ b3,
    float* __restrict__ out) {
    __shared__ unsigned short sW3[64 * K3S];
    __shared__ unsigned short sA[64 * K3S];

    int t = threadIdx.x;
    int n0 = blockIdx.x * 64;

    {
        const uint4* wv = (const uint4*)W3T;
        uint4* sv = (uint4*)sW3;
        for (int i = t; i < 64 * K3S * 2 / 16; i += 256) sv[i] = wv[i];
    }
    {
        int nL = t >> 2, sub = t & 3;
        int node = n0 + nL;
        uint4* arow = (uint4*)(sA + nL * K3S);
        if (node < NN) {
            const uint4* xs = (const uint4*)(xb + (size_t)node * H);
            arow[sub * 2]     = xs[sub * 2];
            arow[sub * 2 + 1] = xs[sub * 2 + 1];
            const float4* av = (const float4*)(agg + (size_t)node * H);
            unsigned tmp[8];
            #pragma unroll
            for (int j = 0; j < 4; j++) {
                float4 v = av[sub * 4 + j];
                tmp[j * 2 + 0] = cvt_pk_bf16(v.x, v.y);
                tmp[j * 2 + 1] = cvt_pk_bf16(v.z, v.w);
            }
            uint4* drow = (uint4*)(sA + nL * K3S + 64 + sub * 16);
            drow[0] = ((const uint4*)tmp)[0];
            drow[1] = ((const uint4*)tmp)[1];
        } else {
            uint4 z = {0, 0, 0, 0};
            arow[sub * 2] = z; arow[sub * 2 + 1] = z;
            uint4* drow = (uint4*)(sA + nL * K3S + 64 + sub * 16);
            drow[0] = z; drow[1] = z;
        }
    }
    __syncthreads();

    int w = t >> 6, lane = t & 63;
    int m = lane & 15, q = lane >> 4;
    int node = n0 + w * 16 + m;   // this lane's node (B-operand col)

    floatx4 acc[4];
    #pragma unroll
    for (int i = 0; i < 4; i++) acc[i] = (floatx4){0.f, 0.f, 0.f, 0.f};
    #pragma unroll
    for (int kt = 0; kt < 4; kt++) {
        short8 bfr = *(const short8*)(sA + (w * 16 + m) * K3S + kt * 32 + q * 8);
        #pragma unroll
        for (int tt = 0; tt < 4; tt++) {
            short8 afr = *(const short8*)(sW3 + (tt * 16 + m) * K3S + kt * 32 + q * 8);
            acc[tt] = __builtin_amdgcn_mfma_f32_16x16x32_bf16(afr, bfr, acc[tt], 0, 0, 0);
        }
    }
    if (node < NN) {
        #pragma unroll
        for (int tt = 0; tt < 4; tt++) {
            float4 bb = *(const float4*)(b3 + tt * 16 + q * 4);
            float4 ov;
            ov.x = silu(acc[tt][0] + bb.x);
            ov.y = silu(acc[tt][1] + bb.y);
            ov.z = silu(acc[tt][2] + bb.z);
            ov.w = silu(acc[tt][3] + bb.w);
            *(float4*)(out + (size_t)node * H + tt * 16 + q * 4) = ov;
        }
    }
}

static inline size_t align256(size_t x) { return (x + 255) & ~(size_t)255; }

extern "C" void kernel_launch(void* const* d_in, const int* in_sizes, int n_in,
                              void* d_out, int out_size, void* d_ws, size_t ws_size,
                              hipStream_t stream) {
    const float* x  = (const float*)d_in[0];
    const int*   ei = (const int*)d_in[1];
    const float* ea = (const float*)d_in[2];
    const float* W1 = (const float*)d_in[3];
    const float* b1 = (const float*)d_in[4];
    const float* W2 = (const float*)d_in[5];
    const float* b2 = (const float*)d_in[6];
    const float* W3 = (const float*)d_in[7];
    const float* b3 = (const float*)d_in[8];
    float* out = (float*)d_out;

    char* ws = (char*)d_ws;
    size_t o = 0;
    float* agg = (float*)(ws + o);                    o = align256(o + (size_t)NN * H * 4);
    unsigned short* xb = (unsigned short*)(ws + o);   o = align256(o + (size_t)NN * H * 2);
    unsigned short* yc = (unsigned short*)(ws + o);   o = align256(o + (size_t)NN * 128 * 2);
    unsigned short* W1abT = (unsigned short*)(ws + o); o = align256(o + 128 * KS * 2);
    unsigned short* W1cT = (unsigned short*)(ws + o); o = align256(o + 64 * 32 * 2);
    unsigned short* W2T = (unsigned short*)(ws + o);  o = align256(o + 64 * KS * 2);
    unsigned short* W3T = (unsigned short*)(ws + o);  o = align256(o + 64 * K3S * 2);
    int* offs = (int*)(ws + o);                       o = align256(o + (size_t)NN * 4);
    int* bsums = (int*)(ws + o);                      o = align256(o + NB1 * 4);
    int* cnt = (int*)(ws + o);                        o = align256(o + (size_t)NN * 4);
    unsigned long long* sSDE = (unsigned long long*)(ws + o); o = align256(o + (size_t)NE * 8);

    int* cursor = cnt;

    hipMemsetAsync(cnt, 0, (size_t)NN * sizeof(int), stream);
    prep_kernel<<<2048, 256, 0, stream>>>(x, W1, b1, W2, W3, ei, xb, W1abT, W1cT, W2T, W3T,
                                          cnt, (float4*)agg);
    scan_block_kernel<<<NB1, 256, 0, stream>>>(cnt, offs, bsums);
    scan_sums_kernel<<<1, 512, 0, stream>>>(bsums);
    scan_add_kernel<<<NB1, 256, 0, stream>>>(offs, bsums, cursor);
    scatter_kernel<<<NE / 256, 256, 0, stream>>>(ei, cursor, sSDE);
    y12_kernel<<<NNB, 256, 0, stream>>>(xb, W1abT, yc);
    edge_kernel<<<NT, 256, 0, stream>>>(yc, ea, sSDE, W1cT, W2T, b2, agg);
    node_kernel<<<NNB, 256, 0, stream>>>(xb, agg, W3T, b3, out);
}

// Round 6
// 425.186 us; speedup vs baseline: 1.2875x; 1.1995x over previous
//
#include <hip/hip_runtime.h>
#include <hip/hip_bf16.h>

#define NE 1600000
#define NN 100000
#define H 64
#define ED 16
#define NT (NE / 64)        // 25000 edge tiles
#define NB1 391             // ceil(NN/256) scan blocks
#define NNB 1563            // ceil(NN/64) node tiles

#define KS  72    // bf16 K-stride for K=64 packs (W1ab, W2, sH rows)
#define K3S 136   // bf16 row stride, node GEMM (K=128)
#define YS  68    // fp32 row stride for message rows

typedef __attribute__((ext_vector_type(8))) short short8;
typedef __attribute__((ext_vector_type(4))) float floatx4;

__device__ __forceinline__ unsigned short f2bf(float f) {
    union { float f; unsigned u; } v; v.f = f;
    unsigned r = v.u + 0x7fff + ((v.u >> 16) & 1);
    return (unsigned short)(r >> 16);
}

__device__ __forceinline__ float bf2f(unsigned short u) {
    union { unsigned u; float f; } v; v.u = ((unsigned)u) << 16;
    return v.f;
}

// v_cvt_pk_bf16_f32: packs 2 f32 -> 2 bf16 (RNE) in ONE VALU op.
__device__ __forceinline__ unsigned cvt_pk_bf16(float lo, float hi) {
    unsigned r;
    asm("v_cvt_pk_bf16_f32 %0, %1, %2" : "=v"(r) : "v"(lo), "v"(hi));
    return r;
}

// silu via fast rcp (1 instr) instead of IEEE divide (~10 instr)
__device__ __forceinline__ float silu(float x) {
    return x * __builtin_amdgcn_rcpf(1.0f + __expf(-x));
}

// ---- prep: x->bf16, weight packs, histogram+rank, agg zero (fused) -----
// Histogram's atomicAdd return value IS the edge's rank within its dst
// bucket -> store it; scatter then needs no atomics at all.
__global__ void prep_kernel(const float* __restrict__ x,
                            const float* __restrict__ W1,
                            const float* __restrict__ b1,
                            const float* __restrict__ W2,
                            const float* __restrict__ W3,
                            const int* __restrict__ ei,
                            unsigned short* __restrict__ xb,
                            unsigned short* __restrict__ W1abT,
                            unsigned short* __restrict__ W1cT,
                            unsigned short* __restrict__ W2T,
                            unsigned short* __restrict__ W3T,
                            int* __restrict__ cnt,
                            int* __restrict__ rank,
                            float4* __restrict__ aggv) {
    int tid = blockIdx.x * blockDim.x + threadIdx.x;
    int nt = gridDim.x * blockDim.x;
    const float4* xv = (const float4*)x;
    uint2* xbv = (uint2*)xb;
    for (int i = tid; i < NN * H / 4; i += nt) {
        float4 v = xv[i];
        uint2 o;
        o.x = cvt_pk_bf16(v.x, v.y);
        o.y = cvt_pk_bf16(v.z, v.w);
        xbv[i] = o;
    }
    // agg zero (replaces hipMemsetAsync dispatch)
    {
        float4 z = {0.f, 0.f, 0.f, 0.f};
        for (int i = tid; i < NN * H / 4; i += nt) aggv[i] = z;
    }
    // W1abT[n][k]: n<64 -> W1[k][n] (x_src part); n in 64..127 -> W1[64+k][n-64]
    for (int i = tid; i < 128 * KS; i += nt) {
        int n = i / KS, k = i % KS;
        W1abT[i] = (k < 64) ? f2bf(W1[(size_t)((n < 64) ? k : 64 + k) * 64 + (n & 63)])
                            : (unsigned short)0;
    }
    // W1cT[n][k]: k<16 -> W1[128+k][n]; k==16 -> b1[n] (bias slot); else 0
    for (int i = tid; i < 64 * 32; i += nt) {
        int n = i / 32, k = i % 32;
        unsigned short v = 0;
        if (k < 16) v = f2bf(W1[(size_t)(128 + k) * 64 + n]);
        else if (k == 16) v = f2bf(b1[n]);
        W1cT[i] = v;
    }
    for (int i = tid; i < 64 * KS; i += nt) {
        int n = i / KS, k = i % KS;
        W2T[i] = (k < 64) ? f2bf(W2[k * 64 + n]) : (unsigned short)0;
    }
    for (int i = tid; i < 64 * K3S; i += nt) {
        int n = i / K3S, k = i % K3S;
        W3T[i] = (k < 128) ? f2bf(W3[k * 64 + n]) : (unsigned short)0;
    }
    // histogram of dst + per-edge rank (coalesced store)
    for (int e = tid; e < NE; e += nt) {
        rank[e] = atomicAdd(&cnt[ei[NE + e]], 1);
    }
}

// ---- counting-sort scan ------------------------------------------------
__global__ void scan_block_kernel(const int* __restrict__ cnt,
                                  int* __restrict__ offs,
                                  int* __restrict__ bsums) {
    __shared__ int tmp[256];
    int b = blockIdx.x, i = threadIdx.x, idx = b * 256 + i;
    int v = (idx < NN) ? cnt[idx] : 0;
    tmp[i] = v;
    __syncthreads();
    #pragma unroll
    for (int off = 1; off < 256; off <<= 1) {
        int t2 = (i >= off) ? tmp[i - off] : 0;
        __syncthreads();
        tmp[i] += t2;
        __syncthreads();
    }
    if (idx < NN) offs[idx] = tmp[i] - v;
    if (i == 255) bsums[b] = tmp[255];
}

__global__ void scan_sums_kernel(int* __restrict__ bsums) {
    __shared__ int tmp[512];
    int i = threadIdx.x;
    int v = (i < NB1) ? bsums[i] : 0;
    tmp[i] = v;
    __syncthreads();
    #pragma unroll
    for (int off = 1; off < 512; off <<= 1) {
        int t2 = (i >= off) ? tmp[i - off] : 0;
        __syncthreads();
        tmp[i] += t2;
        __syncthreads();
    }
    if (i < NB1) bsums[i] = tmp[i] - v;
}

__global__ void scan_add_kernel(int* __restrict__ offs,
                                const int* __restrict__ bsums) {
    int b = blockIdx.x, idx = b * 256 + threadIdx.x;
    if (idx < NN) {
        offs[idx] += bsums[b];
    }
}

// packed sorted-edge record: src(17b) | dst(17b)<<17 | e(21b)<<34
// atomic-free: pos = offs[dst] + rank[e] (rank from prep's histogram)
__global__ void scatter_kernel(const int* __restrict__ ei,
                               const int* __restrict__ offs,
                               const int* __restrict__ rank,
                               unsigned long long* __restrict__ sSDE) {
    int e = blockIdx.x * 256 + threadIdx.x;   // grid 6250 x 256 == NE
    int src = ei[e], dst = ei[NE + e];
    int pos = offs[dst] + rank[e];
    unsigned long long v = (unsigned long long)src
                         | ((unsigned long long)dst << 17)
                         | ((unsigned long long)e << 34);
    sSDE[pos] = v;
}

// ---- y12: yc[node] = [x@W1a | x@W1b] in bf16 (transposed MFMA) ---------
__global__ __launch_bounds__(256) void y12_kernel(
    const unsigned short* __restrict__ xb,
    const unsigned short* __restrict__ W1abT,
    unsigned short* __restrict__ yc) {
    __shared__ unsigned short sW[128 * KS];   // 18432 B
    int t = threadIdx.x;
    {
        const uint4* wv = (const uint4*)W1abT;
        uint4* sv = (uint4*)sW;
        for (int i = t; i < 128 * KS * 2 / 16; i += 256) sv[i] = wv[i];
    }
    __syncthreads();

    int lane = t & 63, w = t >> 6;
    int m = lane & 15, q = lane >> 4;
    int n0 = blockIdx.x * 64;
    int node = n0 + w * 16 + m;               // this lane's node (B-operand col)
    int nclamp = (node < NN) ? node : (NN - 1);

    floatx4 acc[8];
    #pragma unroll
    for (int i = 0; i < 8; i++) acc[i] = (floatx4){0.f, 0.f, 0.f, 0.f};
    #pragma unroll
    for (int kt = 0; kt < 2; kt++) {
        short8 bfr = *(const short8*)(xb + (size_t)nclamp * H + kt * 32 + q * 8);
        #pragma unroll
        for (int tt = 0; tt < 8; tt++) {
            short8 afr = *(const short8*)(sW + (tt * 16 + m) * KS + kt * 32 + q * 8);
            acc[tt] = __builtin_amdgcn_mfma_f32_16x16x32_bf16(afr, bfr, acc[tt], 0, 0, 0);
        }
    }
    // C' = y^T: lane holds node=node, channels tt*16+q*4+r (contiguous)
    if (node < NN) {
        #pragma unroll
        for (int tt = 0; tt < 8; tt++) {
            uint2 o;
            o.x = cvt_pk_bf16(acc[tt][0], acc[tt][1]);
            o.y = cvt_pk_bf16(acc[tt][2], acc[tt][3]);
            *(uint2*)(yc + (size_t)node * 128 + tt * 16 + q * 4) = o;
        }
    }
}

// ---- edge: h = silu(y1[src]+y2[dst]+ea@W1c+b1); m = silu(h@W2+b2); agg --
// Barrier-free + per-wave LDS slabs (sH/sM aliased, disjoint lifetimes
// within the owning wave; DS ops in-order per wave).
__global__ __launch_bounds__(256, 8) void edge_kernel(
    const unsigned short* __restrict__ yc,
    const float* __restrict__ ea,
    const unsigned long long* __restrict__ sSDE,
    const unsigned short* __restrict__ W1cT,
    const unsigned short* __restrict__ W2T,
    const float* __restrict__ b2,
    float* __restrict__ agg) {
    __shared__ float sWS[4][1088];            // 4 x 4352 B wave slabs
    __shared__ int sDst[64];

    int t = threadIdx.x;
    int lane = t & 63, w = t >> 6;
    int m = lane & 15, q = lane >> 4;
    int E = w * 16 + m;          // this lane's edge row within the 64-tile

    unsigned long long sde = sSDE[(size_t)blockIdx.x * 64 + E];
    int src = (int)(sde & 0x1FFFF);
    int dst = (int)((sde >> 17) & 0x1FFFF);
    int e   = (int)(sde >> 34);
    if (q == 0) sDst[E] = dst;

    // identity A-fragments (2 distinct; even/odd tt repeat the pattern).
    union uf { unsigned u[4]; short8 s; };
    uf idA, idB;
    {
        unsigned val = (m & 1) ? 0x3F800000u : 0x00003F80u;
        int wsel = (m >> 1) & 3;
        bool gA = (q == (m >> 3));
        bool gB = (q == 2 + (m >> 3));
        #pragma unroll
        for (int i = 0; i < 4; i++) {
            idA.u[i] = (gA && wsel == i) ? val : 0u;
            idB.u[i] = (gB && wsel == i) ? val : 0u;
        }
    }

    // B-fragments: scattered 16B gathers of y1[src], y2[dst] (bf16)
    short8 y1f0 = *(const short8*)(yc + (size_t)src * 128 + q * 8);
    short8 y1f1 = *(const short8*)(yc + (size_t)src * 128 + 32 + q * 8);
    short8 y2f0 = *(const short8*)(yc + (size_t)dst * 128 + 64 + q * 8);
    short8 y2f1 = *(const short8*)(yc + (size_t)dst * 128 + 96 + q * 8);

    // GEMM1 B-operand from ea (K=32 with bias slot at k=16)
    short8 bf1 = {0, 0, 0, 0, 0, 0, 0, 0};
    if (q < 2) {
        const float4* p = (const float4*)(ea + (size_t)e * ED + q * 8);
        float4 v0 = p[0], v1 = p[1];
        union { unsigned u[4]; short8 s; } ub;
        ub.u[0] = cvt_pk_bf16(v0.x, v0.y);
        ub.u[1] = cvt_pk_bf16(v0.z, v0.w);
        ub.u[2] = cvt_pk_bf16(v1.x, v1.y);
        ub.u[3] = cvt_pk_bf16(v1.z, v1.w);
        bf1 = ub.s;
    } else if (q == 2) {
        bf1[0] = (short)0x3F80;   // k=16 -> multiplies b1 row
    }

    // GEMM1: pre = ea@W1c + b1 + y1[src] + y2[dst], all inside MFMA accs
    floatx4 acc[4];
    #pragma unroll
    for (int tt = 0; tt < 4; tt++) {
        short8 w1c = *(const short8*)(W1cT + (tt * 16 + m) * 32 + q * 8);
        floatx4 a = (floatx4){0.f, 0.f, 0.f, 0.f};
        a = __builtin_amdgcn_mfma_f32_16x16x32_bf16(w1c, bf1, a, 0, 0, 0);
        short8 idt = (tt & 1) ? idB.s : idA.s;
        a = __builtin_amdgcn_mfma_f32_16x16x32_bf16(idt, (tt >> 1) ? y1f1 : y1f0, a, 0, 0, 0);
        a = __builtin_amdgcn_mfma_f32_16x16x32_bf16(idt, (tt >> 1) ? y2f1 : y2f0, a, 0, 0, 0);
        acc[tt] = a;
    }

    // epi1: h = silu(pre) -> bf16 -> sH rows in this wave's slab
    unsigned short* sHw = (unsigned short*)sWS[w];
    #pragma unroll
    for (int tt = 0; tt < 4; tt++) {
        uint2 hp;
        hp.x = cvt_pk_bf16(silu(acc[tt][0]), silu(acc[tt][1]));
        hp.y = cvt_pk_bf16(silu(acc[tt][2]), silu(acc[tt][3]));
        *(uint2*)(sHw + m * KS + tt * 16 + q * 4) = hp;
    }

    // GEMM2: C2' = (h@W2)^T ; h fragment as B-operand (intra-wave sH read)
    floatx4 acc2[4];
    #pragma unroll
    for (int i = 0; i < 4; i++) acc2[i] = (floatx4){0.f, 0.f, 0.f, 0.f};
    #pragma unroll
    for (int kt = 0; kt < 2; kt++) {
        short8 hfr = *(const short8*)(sHw + m * KS + kt * 32 + q * 8);
        #pragma unroll
        for (int tt = 0; tt < 4; tt++) {
            short8 w2 = *(const short8*)(W2T + (tt * 16 + m) * KS + kt * 32 + q * 8);
            acc2[tt] = __builtin_amdgcn_mfma_f32_16x16x32_bf16(w2, hfr, acc2[tt], 0, 0, 0);
        }
    }

    // epi2: messages -> sM rows in this wave's slab (aliases sH; safe)
    float* sMw = sWS[w];
    #pragma unroll
    for (int tt = 0; tt < 4; tt++) {
        float4 bb = *(const float4*)(b2 + tt * 16 + q * 4);
        float4 mv;
        mv.x = silu(acc2[tt][0] + bb.x);
        mv.y = silu(acc2[tt][1] + bb.y);
        mv.z = silu(acc2[tt][2] + bb.z);
        mv.w = silu(acc2[tt][3] + bb.w);
        *(float4*)(sMw + m * YS + tt * 16 + q * 4) = mv;
    }

    // segment-reduce: wave w reduces its own 16 rows, lane = column
    {
        int c = lane;
        float s = 0.f;
        int cur = sDst[w * 16];
        #pragma unroll
        for (int r = 0; r < 16; r++) {
            int d = sDst[w * 16 + r];
            if (d != cur) {
                atomicAdd(&agg[(size_t)cur * H + c], s);
                s = 0.f;
                cur = d;
            }
            s += sMw[r * YS + c];
        }
        atomicAdd(&agg[(size_t)cur * H + c], s);
    }
}

// ---- node MLP (transposed MFMA) ----------------------------------------
__global__ __launch_bounds__(256) void node_kernel(
    const unsigned short* __restrict__ xb,
    const float* __restrict__ agg,
    const unsigned short* __restrict__ W3T,
    const float* __restrict__ b3,
    float* __restrict__ out) {
    __shared__ unsigned short sW3[64 * K3S];
    __shared__ unsigned short sA[64 * K3S];

    int t = threadIdx.x;
    int n0 = blockIdx.x * 64;

    {
        const uint4* wv = (const uint4*)W3T;
        uint4* sv = (uint4*)sW3;
        for (int i = t; i < 64 * K3S * 2 / 16; i += 256) sv[i] = wv[i];
    }
    {
        int nL = t >> 2, sub = t & 3;
        int node = n0 + nL;
        uint4* arow = (uint4*)(sA + nL * K3S);
        if (node < NN) {
            const uint4* xs = (const uint4*)(xb + (size_t)node * H);
            arow[sub * 2]     = xs[sub * 2];
            arow[sub * 2 + 1] = xs[sub * 2 + 1];
            const float4* av = (const float4*)(agg + (size_t)node * H);
            unsigned tmp[8];
            #pragma unroll
            for (int j = 0; j < 4; j++) {
                float4 v = av[sub * 4 + j];
                tmp[j * 2 + 0] = cvt_pk_bf16(v.x, v.y);
                tmp[j * 2 + 1] = cvt_pk_bf16(v.z, v.w);
            }
            uint4* drow = (uint4*)(sA + nL * K3S + 64 + sub * 16);
            drow[0] = ((const uint4*)tmp)[0];
            drow[1] = ((const uint4*)tmp)[1];
        } else {
            uint4 z = {0, 0, 0, 0};
            arow[sub * 2] = z; arow[sub * 2 + 1] = z;
            uint4* drow = (uint4*)(sA + nL * K3S + 64 + sub * 16);
            drow[0] = z; drow[1] = z;
        }
    }
    __syncthreads();

    int w = t >> 6, lane = t & 63;
    int m = lane & 15, q = lane >> 4;
    int node = n0 + w * 16 + m;   // this lane's node (B-operand col)

    floatx4 acc[4];
    #pragma unroll
    for (int i = 0; i < 4; i++) acc[i] = (floatx4){0.f, 0.f, 0.f, 0.f};
    #pragma unroll
    for (int kt = 0; kt < 4; kt++) {
        short8 bfr = *(const short8*)(sA + (w * 16 + m) * K3S + kt * 32 + q * 8);
        #pragma unroll
        for (int tt = 0; tt < 4; tt++) {
            short8 afr = *(const short8*)(sW3 + (tt * 16 + m) * K3S + kt * 32 + q * 8);
            acc[tt] = __builtin_amdgcn_mfma_f32_16x16x32_bf16(afr, bfr, acc[tt], 0, 0, 0);
        }
    }
    if (node < NN) {
        #pragma unroll
        for (int tt = 0; tt < 4; tt++) {
            float4 bb = *(const float4*)(b3 + tt * 16 + q * 4);
            float4 ov;
            ov.x = silu(acc[tt][0] + bb.x);
            ov.y = silu(acc[tt][1] + bb.y);
            ov.z = silu(acc[tt][2] + bb.z);
            ov.w = silu(acc[tt][3] + bb.w);
            *(float4*)(out + (size_t)node * H + tt * 16 + q * 4) = ov;
        }
    }
}

static inline size_t align256(size_t x) { return (x + 255) & ~(size_t)255; }

extern "C" void kernel_launch(void* const* d_in, const int* in_sizes, int n_in,
                              void* d_out, int out_size, void* d_ws, size_t ws_size,
                              hipStream_t stream) {
    const float* x  = (const float*)d_in[0];
    const int*   ei = (const int*)d_in[1];
    const float* ea = (const float*)d_in[2];
    const float* W1 = (const float*)d_in[3];
    const float* b1 = (const float*)d_in[4];
    const float* W2 = (const float*)d_in[5];
    const float* b2 = (const float*)d_in[6];
    const float* W3 = (const float*)d_in[7];
    const float* b3 = (const float*)d_in[8];
    float* out = (float*)d_out;

    char* ws = (char*)d_ws;
    size_t o = 0;
    float* agg = (float*)(ws + o);                    o = align256(o + (size_t)NN * H * 4);
    unsigned short* xb = (unsigned short*)(ws + o);   o = align256(o + (size_t)NN * H * 2);
    unsigned short* yc = (unsigned short*)(ws + o);   o = align256(o + (size_t)NN * 128 * 2);
    unsigned short* W1abT = (unsigned short*)(ws + o); o = align256(o + 128 * KS * 2);
    unsigned short* W1cT = (unsigned short*)(ws + o); o = align256(o + 64 * 32 * 2);
    unsigned short* W2T = (unsigned short*)(ws + o);  o = align256(o + 64 * KS * 2);
    unsigned short* W3T = (unsigned short*)(ws + o);  o = align256(o + 64 * K3S * 2);
    int* offs = (int*)(ws + o);                       o = align256(o + (size_t)NN * 4);
    int* bsums = (int*)(ws + o);                      o = align256(o + NB1 * 4);
    int* cnt = (int*)(ws + o);                        o = align256(o + (size_t)NN * 4);
    int* rank = (int*)(ws + o);                       o = align256(o + (size_t)NE * 4);
    unsigned long long* sSDE = (unsigned long long*)(ws + o); o = align256(o + (size_t)NE * 8);

    hipMemsetAsync(cnt, 0, (size_t)NN * sizeof(int), stream);
    prep_kernel<<<2048, 256, 0, stream>>>(x, W1, b1, W2, W3, ei, xb, W1abT, W1cT, W2T, W3T,
                                          cnt, rank, (float4*)agg);
    scan_block_kernel<<<NB1, 256, 0, stream>>>(cnt, offs, bsums);
    scan_sums_kernel<<<1, 512, 0, stream>>>(bsums);
    scan_add_kernel<<<NB1, 256, 0, stream>>>(offs, bsums);
    scatter_kernel<<<NE / 256, 256, 0, stream>>>(ei, offs, rank, sSDE);
    y12_kernel<<<NNB, 256, 0, stream>>>(xb, W1abT, yc);
    edge_kernel<<<NT, 256, 0, stream>>>(yc, ea, sSDE, W1cT, W2T, b2, agg);
    node_kernel<<<NNB, 256, 0, stream>>>(xb, agg, W3T, b3, out);
}

// Round 7
// 424.087 us; speedup vs baseline: 1.2908x; 1.0026x over previous
//
#include <hip/hip_runtime.h>
#include <hip/hip_bf16.h>

#define NE 1600000
#define NN 100000
#define H 64
#define ED 16
#define NT (NE / 64)        // 25000 edge tiles
#define NB1 391             // ceil(NN/256) scan blocks
#define NNB 1563            // ceil(NN/64) node tiles
#define NSB 6250            // scatter blocks (NE/256)
#define NFB (NSB + NNB)     // fused scatter+y12 grid = 7813

#define KS  72    // bf16 K-stride for K=64 packs (W1ab, W2, sH rows)
#define K3S 136   // bf16 row stride, node GEMM (K=128)
#define YS  68    // fp32 row stride for message rows

typedef __attribute__((ext_vector_type(8))) short short8;
typedef __attribute__((ext_vector_type(4))) float floatx4;

__device__ __forceinline__ unsigned short f2bf(float f) {
    union { float f; unsigned u; } v; v.f = f;
    unsigned r = v.u + 0x7fff + ((v.u >> 16) & 1);
    return (unsigned short)(r >> 16);
}

// v_cvt_pk_bf16_f32: packs 2 f32 -> 2 bf16 (RNE) in ONE VALU op.
__device__ __forceinline__ unsigned cvt_pk_bf16(float lo, float hi) {
    unsigned r;
    asm("v_cvt_pk_bf16_f32 %0, %1, %2" : "=v"(r) : "v"(lo), "v"(hi));
    return r;
}

// silu via fast rcp (1 instr) instead of IEEE divide (~10 instr)
__device__ __forceinline__ float silu(float x) {
    return x * __builtin_amdgcn_rcpf(1.0f + __expf(-x));
}

// ---- prep: x->bf16, weight packs, histogram+rank, agg zero (fused) -----
// Histogram's atomicAdd return value IS the edge's rank within its dst
// bucket -> store it; scatter then needs no atomics at all.
__global__ void prep_kernel(const float* __restrict__ x,
                            const float* __restrict__ W1,
                            const float* __restrict__ b1,
                            const float* __restrict__ W2,
                            const float* __restrict__ W3,
                            const int* __restrict__ ei,
                            unsigned short* __restrict__ xb,
                            unsigned short* __restrict__ W1abT,
                            unsigned short* __restrict__ W1cT,
                            unsigned short* __restrict__ W2T,
                            unsigned short* __restrict__ W3T,
                            int* __restrict__ cnt,
                            int* __restrict__ rank,
                            float4* __restrict__ aggv) {
    int tid = blockIdx.x * blockDim.x + threadIdx.x;
    int nt = gridDim.x * blockDim.x;
    const float4* xv = (const float4*)x;
    uint2* xbv = (uint2*)xb;
    for (int i = tid; i < NN * H / 4; i += nt) {
        float4 v = xv[i];
        uint2 o;
        o.x = cvt_pk_bf16(v.x, v.y);
        o.y = cvt_pk_bf16(v.z, v.w);
        xbv[i] = o;
    }
    // agg zero (replaces hipMemsetAsync dispatch)
    {
        float4 z = {0.f, 0.f, 0.f, 0.f};
        for (int i = tid; i < NN * H / 4; i += nt) aggv[i] = z;
    }
    // W1abT[n][k]: n<64 -> W1[k][n] (x_src part); n in 64..127 -> W1[64+k][n-64]
    for (int i = tid; i < 128 * KS; i += nt) {
        int n = i / KS, k = i % KS;
        W1abT[i] = (k < 64) ? f2bf(W1[(size_t)((n < 64) ? k : 64 + k) * 64 + (n & 63)])
                            : (unsigned short)0;
    }
    // W1cT[n][k]: k<16 -> W1[128+k][n]; k==16 -> b1[n] (bias slot); else 0
    for (int i = tid; i < 64 * 32; i += nt) {
        int n = i / 32, k = i % 32;
        unsigned short v = 0;
        if (k < 16) v = f2bf(W1[(size_t)(128 + k) * 64 + n]);
        else if (k == 16) v = f2bf(b1[n]);
        W1cT[i] = v;
    }
    for (int i = tid; i < 64 * KS; i += nt) {
        int n = i / KS, k = i % KS;
        W2T[i] = (k < 64) ? f2bf(W2[k * 64 + n]) : (unsigned short)0;
    }
    for (int i = tid; i < 64 * K3S; i += nt) {
        int n = i / K3S, k = i % K3S;
        W3T[i] = (k < 128) ? f2bf(W3[k * 64 + n]) : (unsigned short)0;
    }
    // histogram of dst + per-edge rank (coalesced store)
    for (int e = tid; e < NE; e += nt) {
        rank[e] = atomicAdd(&cnt[ei[NE + e]], 1);
    }
}

// ---- counting-sort scan ------------------------------------------------
__global__ void scan_block_kernel(const int* __restrict__ cnt,
                                  int* __restrict__ offs,
                                  int* __restrict__ bsums) {
    __shared__ int tmp[256];
    int b = blockIdx.x, i = threadIdx.x, idx = b * 256 + i;
    int v = (idx < NN) ? cnt[idx] : 0;
    tmp[i] = v;
    __syncthreads();
    #pragma unroll
    for (int off = 1; off < 256; off <<= 1) {
        int t2 = (i >= off) ? tmp[i - off] : 0;
        __syncthreads();
        tmp[i] += t2;
        __syncthreads();
    }
    if (idx < NN) offs[idx] = tmp[i] - v;
    if (i == 255) bsums[b] = tmp[255];
}

__global__ void scan_sums_kernel(int* __restrict__ bsums) {
    __shared__ int tmp[512];
    int i = threadIdx.x;
    int v = (i < NB1) ? bsums[i] : 0;
    tmp[i] = v;
    __syncthreads();
    #pragma unroll
    for (int off = 1; off < 512; off <<= 1) {
        int t2 = (i >= off) ? tmp[i - off] : 0;
        __syncthreads();
        tmp[i] += t2;
        __syncthreads();
    }
    if (i < NB1) bsums[i] = tmp[i] - v;
}

// ---- fused scatter + y12 -----------------------------------------------
// Two independent pipeline stages co-scheduled in one dispatch so y12's
// MFMA/stream work executes in the shadow of scatter's random-store
// latency. Role split by blockIdx: bid%5==0 -> y12 tile bid/5 (1563
// tiles); else scatter slice (6250 slices). scan_add is folded into the
// scatter address: pos = offs[dst] + bsums[dst>>8] + rank[e].
__global__ __launch_bounds__(256) void scatter_y12_kernel(
    const int* __restrict__ ei,
    const int* __restrict__ offs,
    const int* __restrict__ bsums,
    const int* __restrict__ rank,
    unsigned long long* __restrict__ sSDE,
    const unsigned short* __restrict__ xb,
    const unsigned short* __restrict__ W1abT,
    unsigned short* __restrict__ yc) {
    __shared__ unsigned short sW[128 * KS];   // 18432 B (y12 role only)
    int bid = blockIdx.x;
    int t = threadIdx.x;

    if (bid % 5 == 0) {
        // ---------------- y12 role: tile = bid/5 ----------------
        {
            const uint4* wv = (const uint4*)W1abT;
            uint4* sv = (uint4*)sW;
            for (int i = t; i < 128 * KS * 2 / 16; i += 256) sv[i] = wv[i];
        }
        __syncthreads();

        int lane = t & 63, w = t >> 6;
        int m = lane & 15, q = lane >> 4;
        int n0 = (bid / 5) * 64;
        int node = n0 + w * 16 + m;           // this lane's node (B-operand col)
        int nclamp = (node < NN) ? node : (NN - 1);

        floatx4 acc[8];
        #pragma unroll
        for (int i = 0; i < 8; i++) acc[i] = (floatx4){0.f, 0.f, 0.f, 0.f};
        #pragma unroll
        for (int kt = 0; kt < 2; kt++) {
            short8 bfr = *(const short8*)(xb + (size_t)nclamp * H + kt * 32 + q * 8);
            #pragma unroll
            for (int tt = 0; tt < 8; tt++) {
                short8 afr = *(const short8*)(sW + (tt * 16 + m) * KS + kt * 32 + q * 8);
                acc[tt] = __builtin_amdgcn_mfma_f32_16x16x32_bf16(afr, bfr, acc[tt], 0, 0, 0);
            }
        }
        if (node < NN) {
            #pragma unroll
            for (int tt = 0; tt < 8; tt++) {
                uint2 o;
                o.x = cvt_pk_bf16(acc[tt][0], acc[tt][1]);
                o.y = cvt_pk_bf16(acc[tt][2], acc[tt][3]);
                *(uint2*)(yc + (size_t)node * 128 + tt * 16 + q * 4) = o;
            }
        }
    } else {
        // ---------------- scatter role ----------------
        int sidx = bid - bid / 5 - 1;         // contiguous [0, 6250)
        int e = sidx * 256 + t;
        int src = ei[e], dst = ei[NE + e];
        int pos = offs[dst] + bsums[dst >> 8] + rank[e];
        unsigned long long v = (unsigned long long)src
                             | ((unsigned long long)dst << 17)
                             | ((unsigned long long)e << 34);
        sSDE[pos] = v;
    }
}

// ---- edge: h = silu(y1[src]+y2[dst]+ea@W1c+b1); m = silu(h@W2+b2); agg --
// Barrier-free + per-wave LDS slabs (sH/sM aliased, disjoint lifetimes
// within the owning wave; DS ops in-order per wave).
__global__ __launch_bounds__(256, 8) void edge_kernel(
    const unsigned short* __restrict__ yc,
    const float* __restrict__ ea,
    const unsigned long long* __restrict__ sSDE,
    const unsigned short* __restrict__ W1cT,
    const unsigned short* __restrict__ W2T,
    const float* __restrict__ b2,
    float* __restrict__ agg) {
    __shared__ float sWS[4][1088];            // 4 x 4352 B wave slabs
    __shared__ int sDst[64];

    int t = threadIdx.x;
    int lane = t & 63, w = t >> 6;
    int m = lane & 15, q = lane >> 4;
    int E = w * 16 + m;          // this lane's edge row within the 64-tile

    unsigned long long sde = sSDE[(size_t)blockIdx.x * 64 + E];
    int src = (int)(sde & 0x1FFFF);
    int dst = (int)((sde >> 17) & 0x1FFFF);
    int e   = (int)(sde >> 34);
    if (q == 0) sDst[E] = dst;

    // identity A-fragments (2 distinct; even/odd tt repeat the pattern).
    union uf { unsigned u[4]; short8 s; };
    uf idA, idB;
    {
        unsigned val = (m & 1) ? 0x3F800000u : 0x00003F80u;
        int wsel = (m >> 1) & 3;
        bool gA = (q == (m >> 3));
        bool gB = (q == 2 + (m >> 3));
        #pragma unroll
        for (int i = 0; i < 4; i++) {
            idA.u[i] = (gA && wsel == i) ? val : 0u;
            idB.u[i] = (gB && wsel == i) ? val : 0u;
        }
    }

    // B-fragments: scattered 16B gathers of y1[src], y2[dst] (bf16)
    short8 y1f0 = *(const short8*)(yc + (size_t)src * 128 + q * 8);
    short8 y1f1 = *(const short8*)(yc + (size_t)src * 128 + 32 + q * 8);
    short8 y2f0 = *(const short8*)(yc + (size_t)dst * 128 + 64 + q * 8);
    short8 y2f1 = *(const short8*)(yc + (size_t)dst * 128 + 96 + q * 8);

    // GEMM1 B-operand from ea (K=32 with bias slot at k=16)
    short8 bf1 = {0, 0, 0, 0, 0, 0, 0, 0};
    if (q < 2) {
        const float4* p = (const float4*)(ea + (size_t)e * ED + q * 8);
        float4 v0 = p[0], v1 = p[1];
        union { unsigned u[4]; short8 s; } ub;
        ub.u[0] = cvt_pk_bf16(v0.x, v0.y);
        ub.u[1] = cvt_pk_bf16(v0.z, v0.w);
        ub.u[2] = cvt_pk_bf16(v1.x, v1.y);
        ub.u[3] = cvt_pk_bf16(v1.z, v1.w);
        bf1 = ub.s;
    } else if (q == 2) {
        bf1[0] = (short)0x3F80;   // k=16 -> multiplies b1 row
    }

    // GEMM1: pre = ea@W1c + b1 + y1[src] + y2[dst], all inside MFMA accs
    floatx4 acc[4];
    #pragma unroll
    for (int tt = 0; tt < 4; tt++) {
        short8 w1c = *(const short8*)(W1cT + (tt * 16 + m) * 32 + q * 8);
        floatx4 a = (floatx4){0.f, 0.f, 0.f, 0.f};
        a = __builtin_amdgcn_mfma_f32_16x16x32_bf16(w1c, bf1, a, 0, 0, 0);
        short8 idt = (tt & 1) ? idB.s : idA.s;
        a = __builtin_amdgcn_mfma_f32_16x16x32_bf16(idt, (tt >> 1) ? y1f1 : y1f0, a, 0, 0, 0);
        a = __builtin_amdgcn_mfma_f32_16x16x32_bf16(idt, (tt >> 1) ? y2f1 : y2f0, a, 0, 0, 0);
        acc[tt] = a;
    }

    // epi1: h = silu(pre) -> bf16 -> sH rows in this wave's slab
    unsigned short* sHw = (unsigned short*)sWS[w];
    #pragma unroll
    for (int tt = 0; tt < 4; tt++) {
        uint2 hp;
        hp.x = cvt_pk_bf16(silu(acc[tt][0]), silu(acc[tt][1]));
        hp.y = cvt_pk_bf16(silu(acc[tt][2]), silu(acc[tt][3]));
        *(uint2*)(sHw + m * KS + tt * 16 + q * 4) = hp;
    }

    // GEMM2: C2' = (h@W2)^T ; h fragment as B-operand (intra-wave sH read)
    floatx4 acc2[4];
    #pragma unroll
    for (int i = 0; i < 4; i++) acc2[i] = (floatx4){0.f, 0.f, 0.f, 0.f};
    #pragma unroll
    for (int kt = 0; kt < 2; kt++) {
        short8 hfr = *(const short8*)(sHw + m * KS + kt * 32 + q * 8);
        #pragma unroll
        for (int tt = 0; tt < 4; tt++) {
            short8 w2 = *(const short8*)(W2T + (tt * 16 + m) * KS + kt * 32 + q * 8);
            acc2[tt] = __builtin_amdgcn_mfma_f32_16x16x32_bf16(w2, hfr, acc2[tt], 0, 0, 0);
        }
    }

    // epi2: messages -> sM rows in this wave's slab (aliases sH; safe)
    float* sMw = sWS[w];
    #pragma unroll
    for (int tt = 0; tt < 4; tt++) {
        float4 bb = *(const float4*)(b2 + tt * 16 + q * 4);
        float4 mv;
        mv.x = silu(acc2[tt][0] + bb.x);
        mv.y = silu(acc2[tt][1] + bb.y);
        mv.z = silu(acc2[tt][2] + bb.z);
        mv.w = silu(acc2[tt][3] + bb.w);
        *(float4*)(sMw + m * YS + tt * 16 + q * 4) = mv;
    }

    // segment-reduce: wave w reduces its own 16 rows, lane = column
    {
        int c = lane;
        float s = 0.f;
        int cur = sDst[w * 16];
        #pragma unroll
        for (int r = 0; r < 16; r++) {
            int d = sDst[w * 16 + r];
            if (d != cur) {
                atomicAdd(&agg[(size_t)cur * H + c], s);
                s = 0.f;
                cur = d;
            }
            s += sMw[r * YS + c];
        }
        atomicAdd(&agg[(size_t)cur * H + c], s);
    }
}

// ---- node MLP (transposed MFMA) ----------------------------------------
__global__ __launch_bounds__(256) void node_kernel(
    const unsigned short* __restrict__ xb,
    const float* __restrict__ agg,
    const unsigned short* __restrict__ W3T,
    const float* __restrict__ b3,
    float* __restrict__ out) {
    __shared__ unsigned short sW3[64 * K3S];
    __shared__ unsigned short sA[64 * K3S];

    int t = threadIdx.x;
    int n0 = blockIdx.x * 64;

    {
        const uint4* wv = (const uint4*)W3T;
        uint4* sv = (uint4*)sW3;
        for (int i = t; i < 64 * K3S * 2 / 16; i += 256) sv[i] = wv[i];
    }
    {
        int nL = t >> 2, sub = t & 3;
        int node = n0 + nL;
        uint4* arow = (uint4*)(sA + nL * K3S);
        if (node < NN) {
            const uint4* xs = (const uint4*)(xb + (size_t)node * H);
            arow[sub * 2]     = xs[sub * 2];
            arow[sub * 2 + 1] = xs[sub * 2 + 1];
            const float4* av = (const float4*)(agg + (size_t)node * H);
            unsigned tmp[8];
            #pragma unroll
            for (int j = 0; j < 4; j++) {
                float4 v = av[sub * 4 + j];
                tmp[j * 2 + 0] = cvt_pk_bf16(v.x, v.y);
                tmp[j * 2 + 1] = cvt_pk_bf16(v.z, v.w);
            }
            uint4* drow = (uint4*)(sA + nL * K3S + 64 + sub * 16);
            drow[0] = ((const uint4*)tmp)[0];
            drow[1] = ((const uint4*)tmp)[1];
        } else {
            uint4 z = {0, 0, 0, 0};
            arow[sub * 2] = z; arow[sub * 2 + 1] = z;
            uint4* drow = (uint4*)(sA + nL * K3S + 64 + sub * 16);
            drow[0] = z; drow[1] = z;
        }
    }
    __syncthreads();

    int w = t >> 6, lane = t & 63;
    int m = lane & 15, q = lane >> 4;
    int node = n0 + w * 16 + m;   // this lane's node (B-operand col)

    floatx4 acc[4];
    #pragma unroll
    for (int i = 0; i < 4; i++) acc[i] = (floatx4){0.f, 0.f, 0.f, 0.f};
    #pragma unroll
    for (int kt = 0; kt < 4; kt++) {
        short8 bfr = *(const short8*)(sA + (w * 16 + m) * K3S + kt * 32 + q * 8);
        #pragma unroll
        for (int tt = 0; tt < 4; tt++) {
            short8 afr = *(const short8*)(sW3 + (tt * 16 + m) * K3S + kt * 32 + q * 8);
            acc[tt] = __builtin_amdgcn_mfma_f32_16x16x32_bf16(afr, bfr, acc[tt], 0, 0, 0);
        }
    }
    if (node < NN) {
        #pragma unroll
        for (int tt = 0; tt < 4; tt++) {
            float4 bb = *(const float4*)(b3 + tt * 16 + q * 4);
            float4 ov;
            ov.x = silu(acc[tt][0] + bb.x);
            ov.y = silu(acc[tt][1] + bb.y);
            ov.z = silu(acc[tt][2] + bb.z);
            ov.w = silu(acc[tt][3] + bb.w);
            *(float4*)(out + (size_t)node * H + tt * 16 + q * 4) = ov;
        }
    }
}

static inline size_t align256(size_t x) { return (x + 255) & ~(size_t)255; }

extern "C" void kernel_launch(void* const* d_in, const int* in_sizes, int n_in,
                              void* d_out, int out_size, void* d_ws, size_t ws_size,
                              hipStream_t stream) {
    const float* x  = (const float*)d_in[0];
    const int*   ei = (const int*)d_in[1];
    const float* ea = (const float*)d_in[2];
    const float* W1 = (const float*)d_in[3];
    const float* b1 = (const float*)d_in[4];
    const float* W2 = (const float*)d_in[5];
    const float* b2 = (const float*)d_in[6];
    const float* W3 = (const float*)d_in[7];
    const float* b3 = (const float*)d_in[8];
    float* out = (float*)d_out;

    char* ws = (char*)d_ws;
    size_t o = 0;
    float* agg = (float*)(ws + o);                    o = align256(o + (size_t)NN * H * 4);
    unsigned short* xb = (unsigned short*)(ws + o);   o = align256(o + (size_t)NN * H * 2);
    unsigned short* yc = (unsigned short*)(ws + o);   o = align256(o + (size_t)NN * 128 * 2);
    unsigned short* W1abT = (unsigned short*)(ws + o); o = align256(o + 128 * KS * 2);
    unsigned short* W1cT = (unsigned short*)(ws + o); o = align256(o + 64 * 32 * 2);
    unsigned short* W2T = (unsigned short*)(ws + o);  o = align256(o + 64 * KS * 2);
    unsigned short* W3T = (unsigned short*)(ws + o);  o = align256(o + 64 * K3S * 2);
    int* offs = (int*)(ws + o);                       o = align256(o + (size_t)NN * 4);
    int* bsums = (int*)(ws + o);                      o = align256(o + NB1 * 4);
    int* cnt = (int*)(ws + o);                        o = align256(o + (size_t)NN * 4);
    int* rank = (int*)(ws + o);                       o = align256(o + (size_t)NE * 4);
    unsigned long long* sSDE = (unsigned long long*)(ws + o); o = align256(o + (size_t)NE * 8);

    hipMemsetAsync(cnt, 0, (size_t)NN * sizeof(int), stream);
    prep_kernel<<<2048, 256, 0, stream>>>(x, W1, b1, W2, W3, ei, xb, W1abT, W1cT, W2T, W3T,
                                          cnt, rank, (float4*)agg);
    scan_block_kernel<<<NB1, 256, 0, stream>>>(cnt, offs, bsums);
    scan_sums_kernel<<<1, 512, 0, stream>>>(bsums);
    scatter_y12_kernel<<<NFB, 256, 0, stream>>>(ei, offs, bsums, rank, sSDE, xb, W1abT, yc);
    edge_kernel<<<NT, 256, 0, stream>>>(yc, ea, sSDE, W1cT, W2T, b2, agg);
    node_kernel<<<NNB, 256, 0, stream>>>(xb, agg, W3T, b3, out);
}